// Round 1
// baseline (146.572 us; speedup 1.0000x reference)
//
#include <hip/hip_runtime.h>
#include <hip/hip_bf16.h>

// Problem: B=8, T=2048, E=1024, H=64 single-head causal attention.
// ws layout: wsT (bf16 [192][1024]) @0 ; kb bf16 [8][2048][64] @1MB ;
//            qb (pre-scaled by 0.125) @3MB ; vT bf16 [8][64][2048] @5MB.

typedef float f32x4 __attribute__((ext_vector_type(4)));
typedef short bf16x8 __attribute__((ext_vector_type(8)));
typedef short bf16x4 __attribute__((ext_vector_type(4)));

#define MFMA16 __builtin_amdgcn_mfma_f32_16x16x32_bf16

__device__ __forceinline__ short f2bf(float f) {
    union { float f; unsigned u; } c; c.f = f;
    unsigned u = c.u;
    return (short)((u + 0x7FFFu + ((u >> 16) & 1u)) >> 16);  // RNE
}

// ---- kernel 0: transpose+convert W -> wsT[192][1024] bf16; Wq rows scaled by 0.125
__global__ __launch_bounds__(256) void prep_w(const float* __restrict__ Wk,
                                              const float* __restrict__ Wq,
                                              const float* __restrict__ Wv,
                                              short* __restrict__ wsT) {
    int idx = blockIdx.x * 256 + threadIdx.x;   // 0..196607
    int r = idx >> 10;                          // output row 0..191
    int k = idx & 1023;
    int mat = r >> 6, c = r & 63;
    const float* W = (mat == 0) ? Wk : (mat == 1) ? Wq : Wv;
    float v = W[k * 64 + c];
    if (mat == 1) v *= 0.125f;                  // fold softmax scale into q
    wsT[r * 1024 + k] = f2bf(v);
}

// ---- kernel 1: projections. wave = 32 rows x 192 cols, K=1024, MFMA 16x16x32.
__global__ __launch_bounds__(256) void proj(const float* __restrict__ x,
                                            const short* __restrict__ wsT,
                                            short* __restrict__ kb,
                                            short* __restrict__ qb,
                                            short* __restrict__ vT) {
    int wave = blockIdx.x * 4 + (threadIdx.x >> 6);   // 0..511
    int lane = threadIdx.x & 63;
    int lr = lane & 15, lg = lane >> 4;
    int t0 = wave * 32;                               // global row base

    f32x4 acc[2][12] = {};

    const float* xr0 = x + (size_t)(t0 + lr) * 1024;
    const float* xr1 = x + (size_t)(t0 + 16 + lr) * 1024;

    for (int k0 = 0; k0 < 1024; k0 += 32) {
        int ko = k0 + lg * 8;
        f32x4 u0 = *(const f32x4*)(xr0 + ko);
        f32x4 u1 = *(const f32x4*)(xr0 + ko + 4);
        f32x4 w0 = *(const f32x4*)(xr1 + ko);
        f32x4 w1 = *(const f32x4*)(xr1 + ko + 4);
        bf16x8 a0, a1;
#pragma unroll
        for (int j = 0; j < 4; ++j) {
            a0[j] = f2bf(u0[j]); a0[4 + j] = f2bf(u1[j]);
            a1[j] = f2bf(w0[j]); a1[4 + j] = f2bf(w1[j]);
        }
#pragma unroll
        for (int nt = 0; nt < 12; ++nt) {
            bf16x8 bf = *(const bf16x8*)(wsT + (nt * 16 + lr) * 1024 + ko);
            acc[0][nt] = MFMA16(a0, bf, acc[0][nt], 0, 0, 0);
            acc[1][nt] = MFMA16(a1, bf, acc[1][nt], 0, 0, 0);
        }
    }

    int b = t0 >> 11;
#pragma unroll
    for (int m = 0; m < 2; ++m) {
        int trow = t0 + m * 16 + lg * 4;              // global row (+r)
#pragma unroll
        for (int nt = 0; nt < 12; ++nt) {
            int mat = nt >> 2;
            int h = (nt & 3) * 16 + lr;
            if (mat == 2) {                            // V -> transposed, pack 4 rows
                bf16x4 pk;
#pragma unroll
                for (int r = 0; r < 4; ++r) pk[r] = f2bf(acc[m][nt][r]);
                *(bf16x4*)(vT + ((size_t)(b * 64 + h) * 2048) + (trow & 2047)) = pk;
            } else {
                short* dst = (mat == 0) ? kb : qb;
#pragma unroll
                for (int r = 0; r < 4; ++r)
                    dst[(size_t)(trow + r) * 64 + h] = f2bf(acc[m][nt][r]);
            }
        }
    }
}

// ---- kernel 2: causal flash attention. wave = 16 q-rows; paired tiles (i,127-i).
__global__ __launch_bounds__(128) void attn(const short* __restrict__ kb,
                                            const short* __restrict__ qb,
                                            const short* __restrict__ vT,
                                            float* __restrict__ out) {
    int widx = threadIdx.x >> 6;
    int lane = threadIdx.x & 63;
    int lr = lane & 15, lg = lane >> 4;
    int job = blockIdx.x * 2 + widx;                  // 0..511
    int b = job >> 6, pr = job & 63;

    __shared__ short lds_p[2][16][40];                // per-wave P tile, stride 40
    short (*P)[40] = lds_p[widx];

    for (int sel = 0; sel < 2; ++sel) {
        int tile = sel ? pr : (127 - pr);
        int t0 = tile * 16;

        const short* qbase = qb + (size_t)(b * 2048 + t0 + lr) * 64 + lg * 8;
        bf16x8 qf0 = *(const bf16x8*)(qbase);
        bf16x8 qf1 = *(const bf16x8*)(qbase + 32);

        f32x4 acc[4] = {};
        float m4[4] = {-1e30f, -1e30f, -1e30f, -1e30f};
        float l4[4] = {0.f, 0.f, 0.f, 0.f};

        int send = t0 + 16;
        for (int s0 = 0; s0 < send; s0 += 32) {
            const short* kbase = kb + (size_t)(b * 2048 + s0 + lr) * 64 + lg * 8;
            bf16x8 k00 = *(const bf16x8*)(kbase);
            bf16x8 k01 = *(const bf16x8*)(kbase + 32);
            bf16x8 k10 = *(const bf16x8*)(kbase + 16 * 64);
            bf16x8 k11 = *(const bf16x8*)(kbase + 16 * 64 + 32);

            f32x4 sa = {}, sb = {};
            sa = MFMA16(qf0, k00, sa, 0, 0, 0);
            sa = MFMA16(qf1, k01, sa, 0, 0, 0);
            sb = MFMA16(qf0, k10, sb, 0, 0, 0);
            sb = MFMA16(qf1, k11, sb, 0, 0, 0);

            if (s0 + 31 > t0) {                       // causal mask (diag blocks)
#pragma unroll
                for (int r = 0; r < 4; ++r) {
                    int t = t0 + lg * 4 + r;
                    if (s0 + lr > t)      sa[r] = -1e30f;
                    if (s0 + 16 + lr > t) sb[r] = -1e30f;
                }
            }

            float f[4];
#pragma unroll
            for (int r = 0; r < 4; ++r) {
                float tm = fmaxf(sa[r], sb[r]);
                tm = fmaxf(tm, __shfl_xor(tm, 1, 16));
                tm = fmaxf(tm, __shfl_xor(tm, 2, 16));
                tm = fmaxf(tm, __shfl_xor(tm, 4, 16));
                tm = fmaxf(tm, __shfl_xor(tm, 8, 16));
                float mn = fmaxf(m4[r], tm);
                float fr = __expf(m4[r] - mn);
                float p0 = __expf(sa[r] - mn);
                float p1 = __expf(sb[r] - mn);
                float rs = p0 + p1;
                rs += __shfl_xor(rs, 1, 16);
                rs += __shfl_xor(rs, 2, 16);
                rs += __shfl_xor(rs, 4, 16);
                rs += __shfl_xor(rs, 8, 16);
                l4[r] = l4[r] * fr + rs;
                m4[r] = mn;
                f[r] = fr;
                P[lg * 4 + r][lr]      = f2bf(p0);
                P[lg * 4 + r][16 + lr] = f2bf(p1);
            }
#pragma unroll
            for (int hnt = 0; hnt < 4; ++hnt)
#pragma unroll
                for (int r = 0; r < 4; ++r) acc[hnt][r] *= f[r];

            bf16x8 pf = *(const bf16x8*)&P[lr][lg * 8];

            const short* vbase = vT + (size_t)b * 64 * 2048 + (size_t)lr * 2048 + s0 + lg * 8;
            acc[0] = MFMA16(pf, *(const bf16x8*)(vbase),             acc[0], 0, 0, 0);
            acc[1] = MFMA16(pf, *(const bf16x8*)(vbase + 16 * 2048), acc[1], 0, 0, 0);
            acc[2] = MFMA16(pf, *(const bf16x8*)(vbase + 32 * 2048), acc[2], 0, 0, 0);
            acc[3] = MFMA16(pf, *(const bf16x8*)(vbase + 48 * 2048), acc[3], 0, 0, 0);
        }

#pragma unroll
        for (int hnt = 0; hnt < 4; ++hnt)
#pragma unroll
            for (int r = 0; r < 4; ++r)
                out[(size_t)(b * 2048 + t0 + lg * 4 + r) * 64 + hnt * 16 + lr] =
                    acc[hnt][r] / l4[r];
    }
}

extern "C" void kernel_launch(void* const* d_in, const int* in_sizes, int n_in,
                              void* d_out, int out_size, void* d_ws, size_t ws_size,
                              hipStream_t stream) {
    (void)in_sizes; (void)n_in; (void)out_size; (void)ws_size;
    const float* x  = (const float*)d_in[0];
    const float* Wk = (const float*)d_in[1];
    const float* Wq = (const float*)d_in[2];
    const float* Wv = (const float*)d_in[3];
    float* out = (float*)d_out;

    char* ws = (char*)d_ws;
    short* wsT = (short*)(ws);                    // 384 KB
    short* kb  = (short*)(ws + (1u << 20));       // 2 MB
    short* qb  = (short*)(ws + (3u << 20));       // 2 MB
    short* vT  = (short*)(ws + (5u << 20));       // 2 MB   (total 7 MB)

    prep_w<<<768, 256, 0, stream>>>(Wk, Wq, Wv, wsT);
    proj  <<<128, 256, 0, stream>>>(x, wsT, kb, qb, vT);
    attn  <<<256, 128, 0, stream>>>(kb, qb, vT, out);
}

// Round 2
// 135.925 us; speedup vs baseline: 1.0783x; 1.0783x over previous
//
#include <hip/hip_runtime.h>
#include <hip/hip_bf16.h>

// B=8, T=2048, E=1024, H=64 single-head causal attention.
// ws: wsT bf16 [192][1024] @0 ; kb bf16 [8][2048][64] @1MB ;
//     qb (pre-scaled 0.125) @3MB ; vT bf16 [8][64][2048] @5MB.

typedef float f32x4 __attribute__((ext_vector_type(4)));
typedef short bf16x8 __attribute__((ext_vector_type(8)));
typedef short bf16x4 __attribute__((ext_vector_type(4)));

#define MFMA16 __builtin_amdgcn_mfma_f32_16x16x32_bf16

__device__ __forceinline__ short f2bf(float f) {
    union { float f; unsigned u; } c; c.f = f;
    unsigned u = c.u;
    return (short)((u + 0x7FFFu + ((u >> 16) & 1u)) >> 16);  // RNE
}

// ---- kernel 0: transpose+convert W -> wsT[192][1024] bf16; Wq rows scaled 0.125
__global__ __launch_bounds__(256) void prep_w(const float* __restrict__ Wk,
                                              const float* __restrict__ Wq,
                                              const float* __restrict__ Wv,
                                              short* __restrict__ wsT) {
    int idx = blockIdx.x * 256 + threadIdx.x;   // 0..196607
    int r = idx >> 10;                          // row 0..191
    int k = idx & 1023;
    int mat = r >> 6, c = r & 63;
    const float* W = (mat == 0) ? Wk : (mat == 1) ? Wq : Wv;
    float v = W[k * 64 + c];
    if (mat == 1) v *= 0.125f;
    wsT[r * 1024 + k] = f2bf(v);
}

// ---- kernel 1: projections. block = 3 waves (one per matrix), 16 rows/block.
__global__ __launch_bounds__(192) void proj(const float* __restrict__ x,
                                            const short* __restrict__ wsT,
                                            short* __restrict__ kb,
                                            short* __restrict__ qb,
                                            short* __restrict__ vT) {
    int w = threadIdx.x >> 6;                   // matrix: 0=k 1=q 2=v
    int lane = threadIdx.x & 63;
    int lr = lane & 15, lg = lane >> 4;
    int t0 = blockIdx.x * 16;                   // global row base (0..16368)

    const float* xr = x + (size_t)(t0 + lr) * 1024;
    const short* wbase = wsT + (size_t)(w * 64) * 1024;

    f32x4 acc[4] = {};

    for (int k0 = 0; k0 < 1024; k0 += 32) {
        int ko = k0 + lg * 8;
        f32x4 u0 = *(const f32x4*)(xr + ko);
        f32x4 u1 = *(const f32x4*)(xr + ko + 4);
        bf16x8 a;
#pragma unroll
        for (int j = 0; j < 4; ++j) { a[j] = f2bf(u0[j]); a[4 + j] = f2bf(u1[j]); }
#pragma unroll
        for (int nt = 0; nt < 4; ++nt) {
            bf16x8 bf = *(const bf16x8*)(wbase + (size_t)(nt * 16 + lr) * 1024 + ko);
            acc[nt] = MFMA16(a, bf, acc[nt], 0, 0, 0);
        }
    }

    int b = t0 >> 11;
    int trow = t0 + lg * 4;
    if (w == 2) {                               // V -> transposed layout
#pragma unroll
        for (int nt = 0; nt < 4; ++nt) {
            int h = nt * 16 + lr;
            bf16x4 pk;
#pragma unroll
            for (int r = 0; r < 4; ++r) pk[r] = f2bf(acc[nt][r]);
            *(bf16x4*)(vT + (size_t)(b * 64 + h) * 2048 + (trow & 2047)) = pk;
        }
    } else {
        short* dst = w ? qb : kb;
#pragma unroll
        for (int nt = 0; nt < 4; ++nt)
#pragma unroll
            for (int r = 0; r < 4; ++r)
                dst[(size_t)(trow + r) * 64 + nt * 16 + lr] = f2bf(acc[nt][r]);
    }
}

// ---- kernel 2: causal flash attention. block = one 16-row q-tile, 4 waves
//      split the kv range (every 4th 32-row block); LDS merge of (m,l,acc).
__global__ __launch_bounds__(256) void attn(const short* __restrict__ kb,
                                            const short* __restrict__ qb,
                                            const short* __restrict__ vT,
                                            float* __restrict__ out) {
    int job = blockIdx.x;                       // 0..1023
    int b = job >> 7;
    int i = job & 127;
    int ti = (i & 1) ? (127 - (i >> 1)) : (i >> 1);   // interleave small/large work
    int t0 = ti * 16;

    int w = threadIdx.x >> 6;                   // 0..3
    int lane = threadIdx.x & 63;
    int lr = lane & 15, lg = lane >> 4;

    __shared__ short lds_p[4][16][40];
    __shared__ float lm[4][16], ll[4][16], lacc[4][16][64];
    short (*P)[40] = lds_p[w];

    const short* qbase = qb + (size_t)(b * 2048 + t0 + lr) * 64 + lg * 8;
    bf16x8 qf0 = *(const bf16x8*)(qbase);
    bf16x8 qf1 = *(const bf16x8*)(qbase + 32);

    f32x4 acc[4] = {};
    float m4[4] = {-1e30f, -1e30f, -1e30f, -1e30f};
    float l4[4] = {0.f, 0.f, 0.f, 0.f};

    int nblk = (t0 + 16 + 31) >> 5;             // 32-row kv blocks
    for (int blk = w; blk < nblk; blk += 4) {
        int s0 = blk * 32;
        const short* kbase = kb + (size_t)(b * 2048 + s0 + lr) * 64 + lg * 8;
        bf16x8 k00 = *(const bf16x8*)(kbase);
        bf16x8 k01 = *(const bf16x8*)(kbase + 32);
        bf16x8 k10 = *(const bf16x8*)(kbase + 16 * 64);
        bf16x8 k11 = *(const bf16x8*)(kbase + 16 * 64 + 32);

        f32x4 sa = {}, sb = {};
        sa = MFMA16(qf0, k00, sa, 0, 0, 0);
        sa = MFMA16(qf1, k01, sa, 0, 0, 0);
        sb = MFMA16(qf0, k10, sb, 0, 0, 0);
        sb = MFMA16(qf1, k11, sb, 0, 0, 0);

        if (s0 + 31 > t0) {                     // causal mask on diagonal blocks
#pragma unroll
            for (int r = 0; r < 4; ++r) {
                int t = t0 + lg * 4 + r;
                if (s0 + lr > t)      sa[r] = -1e30f;
                if (s0 + 16 + lr > t) sb[r] = -1e30f;
            }
        }

        float f[4];
#pragma unroll
        for (int r = 0; r < 4; ++r) {
            float tm = fmaxf(sa[r], sb[r]);
            tm = fmaxf(tm, __shfl_xor(tm, 1, 16));
            tm = fmaxf(tm, __shfl_xor(tm, 2, 16));
            tm = fmaxf(tm, __shfl_xor(tm, 4, 16));
            tm = fmaxf(tm, __shfl_xor(tm, 8, 16));
            float mn = fmaxf(m4[r], tm);
            float fr = __expf(m4[r] - mn);
            float p0 = __expf(sa[r] - mn);
            float p1 = __expf(sb[r] - mn);
            float rs = p0 + p1;
            rs += __shfl_xor(rs, 1, 16);
            rs += __shfl_xor(rs, 2, 16);
            rs += __shfl_xor(rs, 4, 16);
            rs += __shfl_xor(rs, 8, 16);
            l4[r] = l4[r] * fr + rs;
            m4[r] = mn;
            f[r] = fr;
            P[lg * 4 + r][lr]      = f2bf(p0);
            P[lg * 4 + r][16 + lr] = f2bf(p1);
        }
#pragma unroll
        for (int hnt = 0; hnt < 4; ++hnt)
#pragma unroll
            for (int r = 0; r < 4; ++r) acc[hnt][r] *= f[r];

        bf16x8 pf = *(const bf16x8*)&P[lr][lg * 8];

        const short* vbase = vT + (size_t)b * 64 * 2048 + (size_t)lr * 2048 + s0 + lg * 8;
        acc[0] = MFMA16(pf, *(const bf16x8*)(vbase),             acc[0], 0, 0, 0);
        acc[1] = MFMA16(pf, *(const bf16x8*)(vbase + 16 * 2048), acc[1], 0, 0, 0);
        acc[2] = MFMA16(pf, *(const bf16x8*)(vbase + 32 * 2048), acc[2], 0, 0, 0);
        acc[3] = MFMA16(pf, *(const bf16x8*)(vbase + 48 * 2048), acc[3], 0, 0, 0);
    }

    // publish per-wave partial state
#pragma unroll
    for (int r = 0; r < 4; ++r) {
        int row = lg * 4 + r;
        lm[w][row] = m4[r];
        ll[w][row] = l4[r];
#pragma unroll
        for (int hnt = 0; hnt < 4; ++hnt)
            lacc[w][row][hnt * 16 + lr] = acc[hnt][r];
    }
    __syncthreads();

    // merge 4 waves' partials; 256 threads x 4 elements = 16x64 outputs
#pragma unroll
    for (int e = 0; e < 4; ++e) {
        int elem = threadIdx.x + e * 256;
        int row = elem >> 6, col = elem & 63;
        float mw0 = lm[0][row], mw1 = lm[1][row], mw2 = lm[2][row], mw3 = lm[3][row];
        float ms = fmaxf(fmaxf(mw0, mw1), fmaxf(mw2, mw3));
        float s0 = __expf(mw0 - ms), s1 = __expf(mw1 - ms);
        float s2 = __expf(mw2 - ms), s3 = __expf(mw3 - ms);
        float lsum = ll[0][row] * s0 + ll[1][row] * s1 + ll[2][row] * s2 + ll[3][row] * s3;
        float asum = lacc[0][row][col] * s0 + lacc[1][row][col] * s1 +
                     lacc[2][row][col] * s2 + lacc[3][row][col] * s3;
        out[(size_t)(b * 2048 + t0 + row) * 64 + col] = asum / lsum;
    }
}

extern "C" void kernel_launch(void* const* d_in, const int* in_sizes, int n_in,
                              void* d_out, int out_size, void* d_ws, size_t ws_size,
                              hipStream_t stream) {
    (void)in_sizes; (void)n_in; (void)out_size; (void)ws_size;
    const float* x  = (const float*)d_in[0];
    const float* Wk = (const float*)d_in[1];
    const float* Wq = (const float*)d_in[2];
    const float* Wv = (const float*)d_in[3];
    float* out = (float*)d_out;

    char* ws = (char*)d_ws;
    short* wsT = (short*)(ws);                  // 384 KB
    short* kb  = (short*)(ws + (1u << 20));     // 2 MB
    short* qb  = (short*)(ws + (3u << 20));     // 2 MB
    short* vT  = (short*)(ws + (5u << 20));     // 2 MB

    prep_w<<<768, 256, 0, stream>>>(Wk, Wq, Wv, wsT);
    proj  <<<1024, 192, 0, stream>>>(x, wsT, kb, qb, vT);
    attn  <<<1024, 256, 0, stream>>>(kb, qb, vT, out);
}

// Round 3
// 126.662 us; speedup vs baseline: 1.1572x; 1.0731x over previous
//
#include <hip/hip_runtime.h>
#include <hip/hip_bf16.h>

// B=8, T=2048, E=1024, H=64 single-head causal attention.
// ws: wsT bf16 [192][1024] @0 ; kb bf16 [8][2048][64] @1MB ;
//     qb (pre-scaled 0.125) @3MB ; vT bf16 [8][64][2048] @5MB.

typedef float f32x4 __attribute__((ext_vector_type(4)));
typedef short bf16x8 __attribute__((ext_vector_type(8)));
typedef short bf16x4 __attribute__((ext_vector_type(4)));

#define MFMA16 __builtin_amdgcn_mfma_f32_16x16x32_bf16

__device__ __forceinline__ short f2bf(float f) {
    union { float f; unsigned u; } c; c.f = f;
    unsigned u = c.u;
    return (short)((u + 0x7FFFu + ((u >> 16) & 1u)) >> 16);  // RNE
}

// ---- kernel 0: transpose+convert W -> wsT[192][1024] bf16; Wq rows scaled 0.125
__global__ __launch_bounds__(256) void prep_w(const float* __restrict__ Wk,
                                              const float* __restrict__ Wq,
                                              const float* __restrict__ Wv,
                                              short* __restrict__ wsT) {
    int idx = blockIdx.x * 256 + threadIdx.x;
    int r = idx >> 10;
    int k = idx & 1023;
    int mat = r >> 6, c = r & 63;
    const float* W = (mat == 0) ? Wk : (mat == 1) ? Wq : Wv;
    float v = W[k * 64 + c];
    if (mat == 1) v *= 0.125f;
    wsT[r * 1024 + k] = f2bf(v);
}

// ---- kernel 1: projections, LDS-staged. Block = 256 thr, BM=32 rows, BK=128.
// Waves: (wm = rows 16*wm.., wn = cols 96*wn..). x staged fp32 via
// global_load_lds (linear dest), granule^(row&7) swizzle on source+read.
__global__ __launch_bounds__(256) void proj(const float* __restrict__ x,
                                            const short* __restrict__ wsT,
                                            short* __restrict__ kb,
                                            short* __restrict__ qb,
                                            short* __restrict__ vT) {
    __shared__ char ldsraw[2 * 16384];          // 2 x [32 rows][128 k] fp32
    int tid = threadIdx.x;
    int w = tid >> 6, lane = tid & 63;
    int wm = w >> 1, wn = w & 1;
    int lr = lane & 15, lg = lane >> 4;
    int t0 = blockIdx.x * 32;

    f32x4 acc[6] = {};

    auto stage = [&](int kt, int buf) {
        int k0 = kt * 128;
#pragma unroll
        for (int s = 0; s < 4; ++s) {
            int G = s * 256 + tid;              // 16B granule index 0..1023
            int row = G >> 5;
            int cg = G & 31;
            int sg = cg ^ (row & 7);            // pre-swizzled source granule
            const float* gp = x + (size_t)(t0 + row) * 1024 + k0 + sg * 4;
            // wave-uniform LDS base; HW adds lane*16
            unsigned base = (unsigned)(buf * 16384 + s * 4096 + w * 1024);
            __builtin_amdgcn_global_load_lds(
                (const __attribute__((address_space(1))) void*)gp,
                (__attribute__((address_space(3))) void*)(ldsraw + base),
                16, 0, 0);
        }
    };

    const short* wrow = wsT + (size_t)(wn * 96 + lr) * 1024;
    int arow = wm * 16 + lr;
    int rx = arow & 7;

    stage(0, 0);
    __syncthreads();

    for (int kt = 0; kt < 8; ++kt) {
        int cur = kt & 1;
        if (kt < 7) stage(kt + 1, cur ^ 1);

        const char* bufp = ldsraw + cur * 16384 + arow * 512;
#pragma unroll
        for (int ks = 0; ks < 4; ++ks) {
            int gk = ks * 8 + lg * 2;
            f32x4 u0 = *(const f32x4*)(bufp + ((gk)     ^ rx) * 16);
            f32x4 u1 = *(const f32x4*)(bufp + ((gk + 1) ^ rx) * 16);
            bf16x8 a;
#pragma unroll
            for (int j = 0; j < 4; ++j) { a[j] = f2bf(u0[j]); a[4 + j] = f2bf(u1[j]); }
            const short* bp = wrow + kt * 128 + ks * 32 + lg * 8;
#pragma unroll
            for (int nt = 0; nt < 6; ++nt) {
                bf16x8 bf = *(const bf16x8*)(bp + (size_t)nt * 16 * 1024);
                acc[nt] = MFMA16(a, bf, acc[nt], 0, 0, 0);
            }
        }
        __syncthreads();                        // drains stage(kt+1) too
    }

    int b = t0 >> 11;
    int tloc = (t0 & 2047) + wm * 16 + lg * 4;  // row-in-batch base (+r)
    int tg = t0 + wm * 16 + lg * 4;             // global row base (+r)
#pragma unroll
    for (int nt = 0; nt < 6; ++nt) {
        int col0 = wn * 96 + nt * 16;
        int mat = col0 >> 6;
        int h = (col0 & 63) + lr;
        if (mat == 2) {                          // V -> transposed layout
            bf16x4 pk;
#pragma unroll
            for (int r = 0; r < 4; ++r) pk[r] = f2bf(acc[nt][r]);
            *(bf16x4*)(vT + (size_t)(b * 64 + h) * 2048 + tloc) = pk;
        } else {
            short* dst = mat ? qb : kb;
#pragma unroll
            for (int r = 0; r < 4; ++r)
                dst[(size_t)(tg + r) * 64 + h] = f2bf(acc[nt][r]);
        }
    }
}

// ---- kernel 2: causal flash attention, swapped QK^T (P lane-local).
// Block = one 16-row q-tile, 4 waves split kv range; LDS merge of (m,l,acc).
__global__ __launch_bounds__(256) void attn(const short* __restrict__ kb,
                                            const short* __restrict__ qb,
                                            const short* __restrict__ vT,
                                            float* __restrict__ out) {
    int job = blockIdx.x;                       // 0..1023
    int b = job >> 7;
    int i = job & 127;
    int ti = (i & 1) ? (127 - (i >> 1)) : (i >> 1);
    int t0 = ti * 16;

    int w = threadIdx.x >> 6;
    int lane = threadIdx.x & 63;
    int lr = lane & 15, lg = lane >> 4;

    __shared__ short lds_p[4][16][40];
    __shared__ float lm[4][16], ll[4][16], lacc[4][16][64];
    short (*P)[40] = lds_p[w];

    const short* qbase = qb + (size_t)(b * 2048 + t0 + lr) * 64 + lg * 8;
    bf16x8 qf0 = *(const bf16x8*)(qbase);
    bf16x8 qf1 = *(const bf16x8*)(qbase + 32);

    f32x4 acc[4] = {};
    float m_s = -1e30f, l_s = 0.f;

    int nblk = (t0 + 47) >> 5;                  // 32-row kv blocks
    for (int blk = w; blk < nblk; blk += 4) {
        int s0 = blk * 32;
        const short* kbase = kb + (size_t)(b * 2048 + s0 + lr) * 64 + lg * 8;
        bf16x8 k00 = *(const bf16x8*)(kbase);
        bf16x8 k01 = *(const bf16x8*)(kbase + 32);
        bf16x8 k10 = *(const bf16x8*)(kbase + 16 * 64);
        bf16x8 k11 = *(const bf16x8*)(kbase + 16 * 64 + 32);

        // S^T tile: lane holds q = t0+lr ; regs hold kv = s0 + lg*4 + r (+16 for sb)
        f32x4 sa = {}, sb = {};
        sa = MFMA16(k00, qf0, sa, 0, 0, 0);
        sa = MFMA16(k01, qf1, sa, 0, 0, 0);
        sb = MFMA16(k10, qf0, sb, 0, 0, 0);
        sb = MFMA16(k11, qf1, sb, 0, 0, 0);

        if (s0 + 31 > t0) {                     // causal: kv > q -> -inf
            int q = t0 + lr;
#pragma unroll
            for (int r = 0; r < 4; ++r) {
                if (s0 + lg * 4 + r > q)      sa[r] = -1e30f;
                if (s0 + 16 + lg * 4 + r > q) sb[r] = -1e30f;
            }
        }

        // per-lane softmax over the 8 regs (one q-row), reduce across lg groups
        float tm = fmaxf(fmaxf(fmaxf(sa[0], sa[1]), fmaxf(sa[2], sa[3])),
                         fmaxf(fmaxf(sb[0], sb[1]), fmaxf(sb[2], sb[3])));
        tm = fmaxf(tm, __shfl_xor(tm, 16));
        tm = fmaxf(tm, __shfl_xor(tm, 32));
        float mn = fmaxf(m_s, tm);
        float fr = __expf(m_s - mn);
        float pa[4], pb[4];
        float rs = 0.f;
#pragma unroll
        for (int r = 0; r < 4; ++r) {
            pa[r] = __expf(sa[r] - mn);
            pb[r] = __expf(sb[r] - mn);
            rs += pa[r] + pb[r];
        }
        rs += __shfl_xor(rs, 16);
        rs += __shfl_xor(rs, 32);
        l_s = l_s * fr + rs;
        m_s = mn;

        bf16x4 pk0, pk1;
#pragma unroll
        for (int r = 0; r < 4; ++r) { pk0[r] = f2bf(pa[r]); pk1[r] = f2bf(pb[r]); }
        *(bf16x4*)&P[lr][lg * 4]      = pk0;    // P[q][kv]
        *(bf16x4*)&P[lr][16 + lg * 4] = pk1;

        // rescale acc: acc rows are q = lg*4+r -> broadcast fr from lane lg*4+r
        float fb0 = __shfl(fr, lg * 4 + 0, 16);
        float fb1 = __shfl(fr, lg * 4 + 1, 16);
        float fb2 = __shfl(fr, lg * 4 + 2, 16);
        float fb3 = __shfl(fr, lg * 4 + 3, 16);
#pragma unroll
        for (int hnt = 0; hnt < 4; ++hnt) {
            acc[hnt][0] *= fb0; acc[hnt][1] *= fb1;
            acc[hnt][2] *= fb2; acc[hnt][3] *= fb3;
        }

        bf16x8 pf = *(const bf16x8*)&P[lr][lg * 8];   // A-frag: row=q, k=kv

        const short* vbase = vT + (size_t)b * 64 * 2048 + (size_t)lr * 2048 + s0 + lg * 8;
        acc[0] = MFMA16(pf, *(const bf16x8*)(vbase),             acc[0], 0, 0, 0);
        acc[1] = MFMA16(pf, *(const bf16x8*)(vbase + 16 * 2048), acc[1], 0, 0, 0);
        acc[2] = MFMA16(pf, *(const bf16x8*)(vbase + 32 * 2048), acc[2], 0, 0, 0);
        acc[3] = MFMA16(pf, *(const bf16x8*)(vbase + 48 * 2048), acc[3], 0, 0, 0);
    }

    // publish per-wave partial state
    if (lg == 0) { lm[w][lr] = m_s; ll[w][lr] = l_s; }
#pragma unroll
    for (int r = 0; r < 4; ++r) {
        int row = lg * 4 + r;
#pragma unroll
        for (int hnt = 0; hnt < 4; ++hnt)
            lacc[w][row][hnt * 16 + lr] = acc[hnt][r];
    }
    __syncthreads();

    // merge 4 waves' partials; 256 threads x 4 elements = 16x64 outputs
#pragma unroll
    for (int e = 0; e < 4; ++e) {
        int elem = threadIdx.x + e * 256;
        int row = elem >> 6, col = elem & 63;
        float mw0 = lm[0][row], mw1 = lm[1][row], mw2 = lm[2][row], mw3 = lm[3][row];
        float ms = fmaxf(fmaxf(mw0, mw1), fmaxf(mw2, mw3));
        float s0 = __expf(mw0 - ms), s1 = __expf(mw1 - ms);
        float s2 = __expf(mw2 - ms), s3 = __expf(mw3 - ms);
        float lsum = ll[0][row] * s0 + ll[1][row] * s1 + ll[2][row] * s2 + ll[3][row] * s3;
        float asum = lacc[0][row][col] * s0 + lacc[1][row][col] * s1 +
                     lacc[2][row][col] * s2 + lacc[3][row][col] * s3;
        out[(size_t)(b * 2048 + t0 + row) * 64 + col] = asum / lsum;
    }
}

extern "C" void kernel_launch(void* const* d_in, const int* in_sizes, int n_in,
                              void* d_out, int out_size, void* d_ws, size_t ws_size,
                              hipStream_t stream) {
    (void)in_sizes; (void)n_in; (void)out_size; (void)ws_size;
    const float* x  = (const float*)d_in[0];
    const float* Wk = (const float*)d_in[1];
    const float* Wq = (const float*)d_in[2];
    const float* Wv = (const float*)d_in[3];
    float* out = (float*)d_out;

    char* ws = (char*)d_ws;
    short* wsT = (short*)(ws);                  // 384 KB
    short* kb  = (short*)(ws + (1u << 20));     // 2 MB
    short* qb  = (short*)(ws + (3u << 20));     // 2 MB
    short* vT  = (short*)(ws + (5u << 20));     // 2 MB

    prep_w<<<768, 256, 0, stream>>>(Wk, Wq, Wv, wsT);
    proj  <<<512, 256, 0, stream>>>(x, wsT, kb, qb, vT);
    attn  <<<1024, 256, 0, stream>>>(kb, qb, vT, out);
}

// Round 4
// 80.640 us; speedup vs baseline: 1.8176x; 1.5707x over previous
//
#include <hip/hip_runtime.h>
#include <hip/hip_bf16.h>

// B=8, T=2048, E=1024, H=64 single-head causal attention.
// ws: wsT bf16 [192][1024] @0 ; kb bf16 [8][2048][64] @1MB ;
//     qb (pre-scaled 0.125) @3MB ; vT bf16 [8][64][2048] @5MB.

typedef float f32x4 __attribute__((ext_vector_type(4)));
typedef short bf16x8 __attribute__((ext_vector_type(8)));
typedef short bf16x4 __attribute__((ext_vector_type(4)));

#define MFMA16 __builtin_amdgcn_mfma_f32_16x16x32_bf16

__device__ __forceinline__ short f2bf(float f) {
    union { float f; unsigned u; } c; c.f = f;
    unsigned u = c.u;
    return (short)((u + 0x7FFFu + ((u >> 16) & 1u)) >> 16);  // RNE
}

// ---- kernel 0: transpose+convert W -> wsT[192][1024] bf16; Wq rows scaled 0.125
__global__ __launch_bounds__(256) void prep_w(const float* __restrict__ Wk,
                                              const float* __restrict__ Wq,
                                              const float* __restrict__ Wv,
                                              short* __restrict__ wsT) {
    int idx = blockIdx.x * 256 + threadIdx.x;
    int r = idx >> 10;
    int k = idx & 1023;
    int mat = r >> 6, c = r & 63;
    const float* W = (mat == 0) ? Wk : (mat == 1) ? Wq : Wv;
    float v = W[k * 64 + c];
    if (mat == 1) v *= 0.125f;
    wsT[r * 1024 + k] = f2bf(v);
}

// ---- kernel 1: projections. Block = 256 thr, BM=32, BK=64, both operands in
// LDS (x fp32 8KB + wsT bf16 24KB, double-buffered = 64KB). XOR-granule
// swizzle: linear LDS dest, inverse-swizzled global source, swizzled ds_read.
__global__ __launch_bounds__(256) void proj(const float* __restrict__ x,
                                            const short* __restrict__ wsT,
                                            short* __restrict__ kb,
                                            short* __restrict__ qb,
                                            short* __restrict__ vT) {
    __shared__ char ldsraw[2 * 8192 + 2 * 24576];   // xbuf[2] then wbuf[2]
    int tid = threadIdx.x;
    int w = tid >> 6, lane = tid & 63;
    int wm = w >> 1, wn = w & 1;
    int lr = lane & 15, lg = lane >> 4;
    int t0 = blockIdx.x * 32;

    f32x4 acc[6] = {};

    auto stage = [&](int kt, int buf) {
        int k0 = kt * 64;
#pragma unroll
        for (int s = 0; s < 2; ++s) {               // x: 32 rows x 16 granules
            int G = s * 256 + tid;
            int row = G >> 4, p = G & 15;
            int g = p ^ (row & 15);
            const float* gp = x + (size_t)(t0 + row) * 1024 + k0 + g * 4;
            unsigned base = (unsigned)(buf * 8192 + s * 4096 + w * 1024);
            __builtin_amdgcn_global_load_lds(
                (const __attribute__((address_space(1))) void*)gp,
                (__attribute__((address_space(3))) void*)(ldsraw + base), 16, 0, 0);
        }
#pragma unroll
        for (int s = 0; s < 6; ++s) {               // wsT: 192 rows x 8 granules
            int G = s * 256 + tid;
            int row = G >> 3, p = G & 7;
            int g = p ^ (row & 7);
            const short* gp = wsT + (size_t)row * 1024 + k0 + g * 8;
            unsigned base = (unsigned)(16384 + buf * 24576 + s * 4096 + w * 1024);
            __builtin_amdgcn_global_load_lds(
                (const __attribute__((address_space(1))) void*)gp,
                (__attribute__((address_space(3))) void*)(ldsraw + base), 16, 0, 0);
        }
    };

    int arow = wm * 16 + lr;                        // 0..31, arow&15 == lr

    stage(0, 0);
    __syncthreads();

    for (int kt = 0; kt < 16; ++kt) {
        int cur = kt & 1;
        if (kt < 15) stage(kt + 1, cur ^ 1);

        const char* xb = ldsraw + cur * 8192 + arow * 256;
        const char* wb = ldsraw + 16384 + cur * 24576;
#pragma unroll
        for (int ks = 0; ks < 2; ++ks) {
            int g0 = ks * 8 + lg * 2;
            f32x4 u0 = *(const f32x4*)(xb + ((g0)     ^ lr) * 16);
            f32x4 u1 = *(const f32x4*)(xb + ((g0 + 1) ^ lr) * 16);
            bf16x8 a;
#pragma unroll
            for (int j = 0; j < 4; ++j) { a[j] = f2bf(u0[j]); a[4 + j] = f2bf(u1[j]); }
            int slot = (ks * 4 + lg) ^ (lr & 7);
#pragma unroll
            for (int nt = 0; nt < 6; ++nt) {
                int brow = wn * 96 + nt * 16 + lr;
                bf16x8 bf = *(const bf16x8*)(wb + brow * 128 + slot * 16);
                acc[nt] = MFMA16(a, bf, acc[nt], 0, 0, 0);
            }
        }
        __syncthreads();                            // also drains stage(kt+1)
    }

    int b = t0 >> 11;
    int tloc = (t0 & 2047) + wm * 16 + lg * 4;
    int tg = t0 + wm * 16 + lg * 4;
#pragma unroll
    for (int nt = 0; nt < 6; ++nt) {
        int col0 = wn * 96 + nt * 16;
        int mat = col0 >> 6;
        int h = (col0 & 63) + lr;
        if (mat == 2) {
            bf16x4 pk;
#pragma unroll
            for (int r = 0; r < 4; ++r) pk[r] = f2bf(acc[nt][r]);
            *(bf16x4*)(vT + (size_t)(b * 64 + h) * 2048 + tloc) = pk;
        } else {
            short* dst = mat ? qb : kb;
#pragma unroll
            for (int r = 0; r < 4; ++r)
                dst[(size_t)(tg + r) * 64 + h] = f2bf(acc[nt][r]);
        }
    }
}

// ---- kernel 2: causal flash attention, swapped QK^T (P lane-local),
// XCD-confined batches, K/V register prefetch pipeline.
__global__ __launch_bounds__(256) void attn(const short* __restrict__ kb,
                                            const short* __restrict__ qb,
                                            const short* __restrict__ vT,
                                            float* __restrict__ out) {
    int bid = blockIdx.x;
    int swz = (bid & 7) * 128 + (bid >> 3);     // one batch per XCD
    int b = swz >> 7;
    int i = swz & 127;
    int ti = (i & 1) ? (127 - (i >> 1)) : (i >> 1);
    int t0 = ti * 16;

    int w = threadIdx.x >> 6;
    int lane = threadIdx.x & 63;
    int lr = lane & 15, lg = lane >> 4;

    __shared__ short lds_p[4][16][40];
    __shared__ float lm[4][16], ll[4][16], lacc[4][16][64];
    short (*P)[40] = lds_p[w];

    const short* qbase = qb + (size_t)(b * 2048 + t0 + lr) * 64 + lg * 8;
    bf16x8 qf0 = *(const bf16x8*)(qbase);
    bf16x8 qf1 = *(const bf16x8*)(qbase + 32);

    const short* kb_b = kb + (size_t)b * 2048 * 64 + (size_t)lr * 64 + lg * 8;
    const short* vb_b = vT + (size_t)b * 64 * 2048 + (size_t)lr * 2048 + lg * 8;

    f32x4 acc[4] = {};
    float m_s = -1e30f, l_s = 0.f;

    int nblk = (t0 + 47) >> 5;

    bf16x8 kc0, kc1, kc2, kc3, vc0, vc1, vc2, vc3;
    int blk = w;
    if (blk < nblk) {
        const short* kp = kb_b + (size_t)blk * 32 * 64;
        kc0 = *(const bf16x8*)(kp);
        kc1 = *(const bf16x8*)(kp + 32);
        kc2 = *(const bf16x8*)(kp + 16 * 64);
        kc3 = *(const bf16x8*)(kp + 16 * 64 + 32);
        const short* vp = vb_b + blk * 32;
        vc0 = *(const bf16x8*)(vp);
        vc1 = *(const bf16x8*)(vp + 16 * 2048);
        vc2 = *(const bf16x8*)(vp + 32 * 2048);
        vc3 = *(const bf16x8*)(vp + 48 * 2048);
    }

    for (; blk < nblk; blk += 4) {
        int s0 = blk * 32;
        bf16x8 kn0, kn1, kn2, kn3, vn0, vn1, vn2, vn3;
        int nxt = blk + 4;
        if (nxt < nblk) {                        // prefetch next tile
            const short* kp = kb_b + (size_t)nxt * 32 * 64;
            kn0 = *(const bf16x8*)(kp);
            kn1 = *(const bf16x8*)(kp + 32);
            kn2 = *(const bf16x8*)(kp + 16 * 64);
            kn3 = *(const bf16x8*)(kp + 16 * 64 + 32);
            const short* vp = vb_b + nxt * 32;
            vn0 = *(const bf16x8*)(vp);
            vn1 = *(const bf16x8*)(vp + 16 * 2048);
            vn2 = *(const bf16x8*)(vp + 32 * 2048);
            vn3 = *(const bf16x8*)(vp + 48 * 2048);
        }

        // S^T: lane holds q = t0+lr ; regs hold kv = s0 + lg*4 + r (+16 for sb)
        f32x4 sa = {}, sb = {};
        sa = MFMA16(kc0, qf0, sa, 0, 0, 0);
        sa = MFMA16(kc1, qf1, sa, 0, 0, 0);
        sb = MFMA16(kc2, qf0, sb, 0, 0, 0);
        sb = MFMA16(kc3, qf1, sb, 0, 0, 0);

        if (s0 + 31 > t0) {
            int q = t0 + lr;
#pragma unroll
            for (int r = 0; r < 4; ++r) {
                if (s0 + lg * 4 + r > q)      sa[r] = -1e30f;
                if (s0 + 16 + lg * 4 + r > q) sb[r] = -1e30f;
            }
        }

        float tm = fmaxf(fmaxf(fmaxf(sa[0], sa[1]), fmaxf(sa[2], sa[3])),
                         fmaxf(fmaxf(sb[0], sb[1]), fmaxf(sb[2], sb[3])));
        tm = fmaxf(tm, __shfl_xor(tm, 16));
        tm = fmaxf(tm, __shfl_xor(tm, 32));
        float mn = fmaxf(m_s, tm);
        float fr = __expf(m_s - mn);
        float pa[4], pb[4];
        float rs = 0.f;
#pragma unroll
        for (int r = 0; r < 4; ++r) {
            pa[r] = __expf(sa[r] - mn);
            pb[r] = __expf(sb[r] - mn);
            rs += pa[r] + pb[r];
        }
        rs += __shfl_xor(rs, 16);
        rs += __shfl_xor(rs, 32);
        l_s = l_s * fr + rs;
        m_s = mn;

        bf16x4 pk0, pk1;
#pragma unroll
        for (int r = 0; r < 4; ++r) { pk0[r] = f2bf(pa[r]); pk1[r] = f2bf(pb[r]); }
        *(bf16x4*)&P[lr][lg * 4]      = pk0;     // P[q][kv]
        *(bf16x4*)&P[lr][16 + lg * 4] = pk1;

        float fb0 = __shfl(fr, lg * 4 + 0, 16);
        float fb1 = __shfl(fr, lg * 4 + 1, 16);
        float fb2 = __shfl(fr, lg * 4 + 2, 16);
        float fb3 = __shfl(fr, lg * 4 + 3, 16);
#pragma unroll
        for (int hnt = 0; hnt < 4; ++hnt) {
            acc[hnt][0] *= fb0; acc[hnt][1] *= fb1;
            acc[hnt][2] *= fb2; acc[hnt][3] *= fb3;
        }

        bf16x8 pf = *(const bf16x8*)&P[lr][lg * 8];

        acc[0] = MFMA16(pf, vc0, acc[0], 0, 0, 0);
        acc[1] = MFMA16(pf, vc1, acc[1], 0, 0, 0);
        acc[2] = MFMA16(pf, vc2, acc[2], 0, 0, 0);
        acc[3] = MFMA16(pf, vc3, acc[3], 0, 0, 0);

        kc0 = kn0; kc1 = kn1; kc2 = kn2; kc3 = kn3;
        vc0 = vn0; vc1 = vn1; vc2 = vn2; vc3 = vn3;
    }

    if (lg == 0) { lm[w][lr] = m_s; ll[w][lr] = l_s; }
#pragma unroll
    for (int r = 0; r < 4; ++r) {
        int row = lg * 4 + r;
#pragma unroll
        for (int hnt = 0; hnt < 4; ++hnt)
            lacc[w][row][hnt * 16 + lr] = acc[hnt][r];
    }
    __syncthreads();

#pragma unroll
    for (int e = 0; e < 4; ++e) {
        int elem = threadIdx.x + e * 256;
        int row = elem >> 6, col = elem & 63;
        float mw0 = lm[0][row], mw1 = lm[1][row], mw2 = lm[2][row], mw3 = lm[3][row];
        float ms = fmaxf(fmaxf(mw0, mw1), fmaxf(mw2, mw3));
        float s0 = __expf(mw0 - ms), s1 = __expf(mw1 - ms);
        float s2 = __expf(mw2 - ms), s3 = __expf(mw3 - ms);
        float lsum = ll[0][row] * s0 + ll[1][row] * s1 + ll[2][row] * s2 + ll[3][row] * s3;
        float asum = lacc[0][row][col] * s0 + lacc[1][row][col] * s1 +
                     lacc[2][row][col] * s2 + lacc[3][row][col] * s3;
        out[(size_t)(b * 2048 + t0 + row) * 64 + col] = asum / lsum;
    }
}

extern "C" void kernel_launch(void* const* d_in, const int* in_sizes, int n_in,
                              void* d_out, int out_size, void* d_ws, size_t ws_size,
                              hipStream_t stream) {
    (void)in_sizes; (void)n_in; (void)out_size; (void)ws_size;
    const float* x  = (const float*)d_in[0];
    const float* Wk = (const float*)d_in[1];
    const float* Wq = (const float*)d_in[2];
    const float* Wv = (const float*)d_in[3];
    float* out = (float*)d_out;

    char* ws = (char*)d_ws;
    short* wsT = (short*)(ws);                  // 384 KB
    short* kb  = (short*)(ws + (1u << 20));     // 2 MB
    short* qb  = (short*)(ws + (3u << 20));     // 2 MB
    short* vT  = (short*)(ws + (5u << 20));     // 2 MB

    prep_w<<<768, 256, 0, stream>>>(Wk, Wq, Wv, wsT);
    proj  <<<512, 256, 0, stream>>>(x, wsT, kb, qb, vT);
    attn  <<<1024, 256, 0, stream>>>(kb, qb, vT, out);
}

// Round 5
// 57.222 us; speedup vs baseline: 2.5615x; 1.4092x over previous
//
#include <hip/hip_runtime.h>
#include <hip/hip_bf16.h>

// B=8, T=2048, E=1024, H=64 single-head causal attention.
// ws: wsT bf16 [192][1024] @0 ; kb bf16 [8][2048][64] @1MB ;
//     qb (pre-scaled 0.125*log2e) @3MB ; vT bf16 [8][64][2048] @5MB.

typedef float f32x4 __attribute__((ext_vector_type(4)));
typedef float f32x16 __attribute__((ext_vector_type(16)));
typedef short bf16x8 __attribute__((ext_vector_type(8)));
typedef short bf16x4 __attribute__((ext_vector_type(4)));
typedef unsigned u32x2 __attribute__((ext_vector_type(2)));

#define MFMA16 __builtin_amdgcn_mfma_f32_16x16x32_bf16
#define MFMA32 __builtin_amdgcn_mfma_f32_32x32x16_bf16

__device__ __forceinline__ short f2bf(float f) {
    union { float f; unsigned u; } c; c.f = f;
    unsigned u = c.u;
    return (short)((u + 0x7FFFu + ((u >> 16) & 1u)) >> 16);  // RNE
}

__device__ __forceinline__ unsigned cvt_pk_bf16(float lo, float hi) {
    unsigned r;
    asm("v_cvt_pk_bf16_f32 %0, %1, %2" : "=v"(r) : "v"(lo), "v"(hi));
    return r;
}

// ---- kernel 0: transpose+convert W -> wsT[192][1024] bf16; Wq scaled 0.125*log2e
__global__ __launch_bounds__(256) void prep_w(const float* __restrict__ Wk,
                                              const float* __restrict__ Wq,
                                              const float* __restrict__ Wv,
                                              short* __restrict__ wsT) {
    int idx = blockIdx.x * 256 + threadIdx.x;
    int r = idx >> 10;
    int k = idx & 1023;
    int mat = r >> 6, c = r & 63;
    const float* W = (mat == 0) ? Wk : (mat == 1) ? Wq : Wv;
    float v = W[k * 64 + c];
    if (mat == 1) v *= 0.125f * 1.44269504088896f;   // fold scale + log2(e)
    wsT[r * 1024 + k] = f2bf(v);
}

// ---- kernel 1: projections (unchanged from round 4; ~19us, near plan).
__global__ __launch_bounds__(256) void proj(const float* __restrict__ x,
                                            const short* __restrict__ wsT,
                                            short* __restrict__ kb,
                                            short* __restrict__ qb,
                                            short* __restrict__ vT) {
    __shared__ char ldsraw[2 * 8192 + 2 * 24576];
    int tid = threadIdx.x;
    int w = tid >> 6, lane = tid & 63;
    int wm = w >> 1, wn = w & 1;
    int lr = lane & 15, lg = lane >> 4;
    int t0 = blockIdx.x * 32;

    f32x4 acc[6] = {};

    auto stage = [&](int kt, int buf) {
        int k0 = kt * 64;
#pragma unroll
        for (int s = 0; s < 2; ++s) {
            int G = s * 256 + tid;
            int row = G >> 4, p = G & 15;
            int g = p ^ (row & 15);
            const float* gp = x + (size_t)(t0 + row) * 1024 + k0 + g * 4;
            unsigned base = (unsigned)(buf * 8192 + s * 4096 + w * 1024);
            __builtin_amdgcn_global_load_lds(
                (const __attribute__((address_space(1))) void*)gp,
                (__attribute__((address_space(3))) void*)(ldsraw + base), 16, 0, 0);
        }
#pragma unroll
        for (int s = 0; s < 6; ++s) {
            int G = s * 256 + tid;
            int row = G >> 3, p = G & 7;
            int g = p ^ (row & 7);
            const short* gp = wsT + (size_t)row * 1024 + k0 + g * 8;
            unsigned base = (unsigned)(16384 + buf * 24576 + s * 4096 + w * 1024);
            __builtin_amdgcn_global_load_lds(
                (const __attribute__((address_space(1))) void*)gp,
                (__attribute__((address_space(3))) void*)(ldsraw + base), 16, 0, 0);
        }
    };

    int arow = wm * 16 + lr;

    stage(0, 0);
    __syncthreads();

    for (int kt = 0; kt < 16; ++kt) {
        int cur = kt & 1;
        if (kt < 15) stage(kt + 1, cur ^ 1);

        const char* xb = ldsraw + cur * 8192 + arow * 256;
        const char* wb = ldsraw + 16384 + cur * 24576;
#pragma unroll
        for (int ks = 0; ks < 2; ++ks) {
            int g0 = ks * 8 + lg * 2;
            f32x4 u0 = *(const f32x4*)(xb + ((g0)     ^ lr) * 16);
            f32x4 u1 = *(const f32x4*)(xb + ((g0 + 1) ^ lr) * 16);
            bf16x8 a;
#pragma unroll
            for (int j = 0; j < 4; ++j) { a[j] = f2bf(u0[j]); a[4 + j] = f2bf(u1[j]); }
            int slot = (ks * 4 + lg) ^ (lr & 7);
#pragma unroll
            for (int nt = 0; nt < 6; ++nt) {
                int brow = wn * 96 + nt * 16 + lr;
                bf16x8 bf = *(const bf16x8*)(wb + brow * 128 + slot * 16);
                acc[nt] = MFMA16(a, bf, acc[nt], 0, 0, 0);
            }
        }
        __syncthreads();
    }

    int b = t0 >> 11;
    int tloc = (t0 & 2047) + wm * 16 + lg * 4;
    int tg = t0 + wm * 16 + lg * 4;
#pragma unroll
    for (int nt = 0; nt < 6; ++nt) {
        int col0 = wn * 96 + nt * 16;
        int mat = col0 >> 6;
        int h = (col0 & 63) + lr;
        if (mat == 2) {
            bf16x4 pk;
#pragma unroll
            for (int r = 0; r < 4; ++r) pk[r] = f2bf(acc[nt][r]);
            *(bf16x4*)(vT + (size_t)(b * 64 + h) * 2048 + tloc) = pk;
        } else {
            short* dst = mat ? qb : kb;
#pragma unroll
            for (int r = 0; r < 4; ++r)
                dst[(size_t)(tg + r) * 64 + h] = f2bf(acc[nt][r]);
        }
    }
}

// ---- kernel 2: causal flash attention, 32x32 swapped MFMA, P in registers.
// Block = 512 thr = 8 waves = one 32-q-row tile, 8-way kv split + LDS merge.
__global__ __launch_bounds__(512, 4) void attn(const short* __restrict__ kb,
                                               const short* __restrict__ qb,
                                               const short* __restrict__ vT,
                                               float* __restrict__ out) {
    int bid = blockIdx.x;
    int b = bid & 7;                             // one batch per XCD
    int i = bid >> 3;                            // 0..63
    int ti = (i & 1) ? (63 - (i >> 1)) : (i >> 1);
    int t0 = ti * 32;

    int w = threadIdx.x >> 6;                    // kv-split lane 0..7
    int lane = threadIdx.x & 63;
    int q = lane & 31, hi = lane >> 5;

    __shared__ float lacc[8][32][65];
    __shared__ float lm[8][32], ll[8][32];

    // Q B-frags: col=q, k-chunk c: h = c*16 + hi*8 + j
    const short* qrow = qb + (size_t)(b * 2048 + t0 + q) * 64 + hi * 8;
    bf16x8 qf0 = *(const bf16x8*)(qrow);
    bf16x8 qf1 = *(const bf16x8*)(qrow + 16);
    bf16x8 qf2 = *(const bf16x8*)(qrow + 32);
    bf16x8 qf3 = *(const bf16x8*)(qrow + 48);

    const short* kb_b = kb + (size_t)b * 2048 * 64 + (size_t)q * 64 + hi * 8;
    const short* vb_b = vT + (size_t)b * 64 * 2048 + (size_t)q * 2048 + hi * 8;

    f32x16 acc0 = {}, acc1 = {};
    float m_s = -1e30f, l_s = 0.f;

    int nblk = ti + 1;                           // 32-kv blocks
    for (int blk = w; blk < nblk; blk += 8) {
        int s0 = blk * 32;

        // K A-frags: row = kv = s0+q(lane), k-chunk c
        const short* krow = kb_b + (size_t)s0 * 64;
        bf16x8 kf0 = *(const bf16x8*)(krow);
        bf16x8 kf1 = *(const bf16x8*)(krow + 16);
        bf16x8 kf2 = *(const bf16x8*)(krow + 32);
        bf16x8 kf3 = *(const bf16x8*)(krow + 48);

        f32x16 S = {};
        S = MFMA32(kf0, qf0, S, 0, 0, 0);
        S = MFMA32(kf1, qf1, S, 0, 0, 0);
        S = MFMA32(kf2, qf2, S, 0, 0, 0);
        S = MFMA32(kf3, qf3, S, 0, 0, 0);

        // V^T A-frags for PV (issue early; consumed after softmax)
        const short* vrow = vb_b + s0;
        bf16x8 vf00 = *(const bf16x8*)(vrow);                 // ht=0, kv c=0
        bf16x8 vf01 = *(const bf16x8*)(vrow + 16);            // ht=0, kv c=1
        bf16x8 vf10 = *(const bf16x8*)(vrow + 32 * 2048);     // ht=1, kv c=0
        bf16x8 vf11 = *(const bf16x8*)(vrow + 32 * 2048 + 16);

        if (blk == ti) {                         // diagonal: mask kv>q
#pragma unroll
            for (int r = 0; r < 16; ++r) {
                int row = (r & 3) + 8 * (r >> 2) + 4 * hi;
                if (row > q) S[r] = -1e30f;
            }
        }

        // lane-local softmax (lane owns q col; 16 kv rows here, partner has rest)
        float tm = S[0];
#pragma unroll
        for (int r = 1; r < 16; ++r) tm = fmaxf(tm, S[r]);
        tm = fmaxf(tm, __shfl_xor(tm, 32));
        float mn = fmaxf(m_s, tm);
        float fr = exp2f(m_s - mn);
        float p[16];
        float rs = 0.f;
#pragma unroll
        for (int r = 0; r < 16; ++r) { p[r] = exp2f(S[r] - mn); rs += p[r]; }
        rs += __shfl_xor(rs, 32);
        l_s = l_s * fr + rs;
        m_s = mn;

        // pack P to bf16 pairs, permlane-swap into PV B-frags
        unsigned pk0 = cvt_pk_bf16(p[0],  p[1]);
        unsigned pk1 = cvt_pk_bf16(p[2],  p[3]);
        unsigned pk2 = cvt_pk_bf16(p[4],  p[5]);
        unsigned pk3 = cvt_pk_bf16(p[6],  p[7]);
        unsigned pk4 = cvt_pk_bf16(p[8],  p[9]);
        unsigned pk5 = cvt_pk_bf16(p[10], p[11]);
        unsigned pk6 = cvt_pk_bf16(p[12], p[13]);
        unsigned pk7 = cvt_pk_bf16(p[14], p[15]);
        u32x2 s02 = __builtin_amdgcn_permlane32_swap(pk0, pk2, false, false);
        u32x2 s13 = __builtin_amdgcn_permlane32_swap(pk1, pk3, false, false);
        u32x2 s46 = __builtin_amdgcn_permlane32_swap(pk4, pk6, false, false);
        u32x2 s57 = __builtin_amdgcn_permlane32_swap(pk5, pk7, false, false);
        union { bf16x8 v; unsigned u[4]; } f0, f1;
        f0.u[0] = s02.x; f0.u[1] = s13.x; f0.u[2] = s02.y; f0.u[3] = s13.y;
        f1.u[0] = s46.x; f1.u[1] = s57.x; f1.u[2] = s46.y; f1.u[3] = s57.y;

        // rescale (fr is lane-local!) then PV
#pragma unroll
        for (int r = 0; r < 16; ++r) { acc0[r] *= fr; acc1[r] *= fr; }

        acc0 = MFMA32(vf00, f0.v, acc0, 0, 0, 0);
        acc0 = MFMA32(vf01, f1.v, acc0, 0, 0, 0);
        acc1 = MFMA32(vf10, f0.v, acc1, 0, 0, 0);
        acc1 = MFMA32(vf11, f1.v, acc1, 0, 0, 0);
    }

    // publish partials
    if (hi == 0) { lm[w][q] = m_s; ll[w][q] = l_s; }
#pragma unroll
    for (int r = 0; r < 16; ++r) {
        int row = (r & 3) + 8 * (r >> 2) + 4 * hi;
        lacc[w][q][row]      = acc0[r];
        lacc[w][q][32 + row] = acc1[r];
    }
    __syncthreads();

    // merge 8 partials; 512 threads x 4 elems = 32x64 outputs
    int tid = threadIdx.x;
#pragma unroll
    for (int e = 0; e < 4; ++e) {
        int elem = e * 512 + tid;
        int row = elem >> 6, col = elem & 63;
        float ms = lm[0][row];
#pragma unroll
        for (int j = 1; j < 8; ++j) ms = fmaxf(ms, lm[j][row]);
        float lsum = 0.f, asum = 0.f;
#pragma unroll
        for (int j = 0; j < 8; ++j) {
            float sj = exp2f(lm[j][row] - ms);
            lsum += ll[j][row] * sj;
            asum += lacc[j][row][col] * sj;
        }
        out[(size_t)(b * 2048 + t0 + row) * 64 + col] = asum / lsum;
    }
}

extern "C" void kernel_launch(void* const* d_in, const int* in_sizes, int n_in,
                              void* d_out, int out_size, void* d_ws, size_t ws_size,
                              hipStream_t stream) {
    (void)in_sizes; (void)n_in; (void)out_size; (void)ws_size;
    const float* x  = (const float*)d_in[0];
    const float* Wk = (const float*)d_in[1];
    const float* Wq = (const float*)d_in[2];
    const float* Wv = (const float*)d_in[3];
    float* out = (float*)d_out;

    char* ws = (char*)d_ws;
    short* wsT = (short*)(ws);                  // 384 KB
    short* kb  = (short*)(ws + (1u << 20));     // 2 MB
    short* qb  = (short*)(ws + (3u << 20));     // 2 MB
    short* vT  = (short*)(ws + (5u << 20));     // 2 MB

    prep_w<<<768, 256, 0, stream>>>(Wk, Wq, Wv, wsT);
    proj  <<<512, 256, 0, stream>>>(x, wsT, kb, qb, vT);
    attn  <<<512, 512, 0, stream>>>(kb, qb, vT, out);
}

// Round 6
// 44.289 us; speedup vs baseline: 3.3094x; 1.2920x over previous
//
#include <hip/hip_runtime.h>
#include <hip/hip_bf16.h>

// B=8, T=2048, E=1024, H=64 single-head causal attention.
// ws: wsT bf16 [192][1024] @0.
// kF/qF @1MB/@3MB: fragment-tiled K/Q, [b][s][c][lane][8]:
//   element = M[b][s*32 + (lane&31)][c*16 + (lane>>5)*8 + j]   (M = K or Q)
// vF @5MB: fragment-tiled V, [b][s][ht][c][lane][8]:
//   element = V[b][s*32 + c*16 + (lane>>5)*8 + j][ht*32 + (lane&31)]

typedef float f32x4 __attribute__((ext_vector_type(4)));
typedef float f32x16 __attribute__((ext_vector_type(16)));
typedef short bf16x8 __attribute__((ext_vector_type(8)));
typedef short bf16x4 __attribute__((ext_vector_type(4)));
typedef unsigned u32x2 __attribute__((ext_vector_type(2)));

#define MFMA16 __builtin_amdgcn_mfma_f32_16x16x32_bf16
#define MFMA32 __builtin_amdgcn_mfma_f32_32x32x16_bf16

__device__ __forceinline__ short f2bf(float f) {
    union { float f; unsigned u; } c; c.f = f;
    unsigned u = c.u;
    return (short)((u + 0x7FFFu + ((u >> 16) & 1u)) >> 16);  // RNE
}

__device__ __forceinline__ unsigned cvt_pk_bf16(float lo, float hi) {
    unsigned r;
    asm("v_cvt_pk_bf16_f32 %0, %1, %2" : "=v"(r) : "v"(lo), "v"(hi));
    return r;
}

// ---- kernel 0: transpose+convert W -> wsT[192][1024] bf16; Wq scaled 0.125*log2e
__global__ __launch_bounds__(256) void prep_w(const float* __restrict__ Wk,
                                              const float* __restrict__ Wq,
                                              const float* __restrict__ Wv,
                                              short* __restrict__ wsT) {
    int idx = blockIdx.x * 256 + threadIdx.x;
    int r = idx >> 10;
    int k = idx & 1023;
    int mat = r >> 6, c = r & 63;
    const float* W = (mat == 0) ? Wk : (mat == 1) ? Wq : Wv;
    float v = W[k * 64 + c];
    if (mat == 1) v *= 0.125f * 1.44269504088896f;   // fold scale + log2(e)
    wsT[r * 1024 + k] = f2bf(v);
}

// ---- kernel 1: projections; epilogue scatters into fragment-tiled layouts.
__global__ __launch_bounds__(256) void proj(const float* __restrict__ x,
                                            const short* __restrict__ wsT,
                                            short* __restrict__ kF,
                                            short* __restrict__ qF,
                                            short* __restrict__ vF) {
    __shared__ char ldsraw[2 * 8192 + 2 * 24576];
    int tid = threadIdx.x;
    int w = tid >> 6, lane = tid & 63;
    int wm = w >> 1, wn = w & 1;
    int lr = lane & 15, lg = lane >> 4;
    int t0 = blockIdx.x * 32;

    f32x4 acc[6] = {};

    auto stage = [&](int kt, int buf) {
        int k0 = kt * 64;
#pragma unroll
        for (int s = 0; s < 2; ++s) {
            int G = s * 256 + tid;
            int row = G >> 4, p = G & 15;
            int g = p ^ (row & 15);
            const float* gp = x + (size_t)(t0 + row) * 1024 + k0 + g * 4;
            unsigned base = (unsigned)(buf * 8192 + s * 4096 + w * 1024);
            __builtin_amdgcn_global_load_lds(
                (const __attribute__((address_space(1))) void*)gp,
                (__attribute__((address_space(3))) void*)(ldsraw + base), 16, 0, 0);
        }
#pragma unroll
        for (int s = 0; s < 6; ++s) {
            int G = s * 256 + tid;
            int row = G >> 3, p = G & 7;
            int g = p ^ (row & 7);
            const short* gp = wsT + (size_t)row * 1024 + k0 + g * 8;
            unsigned base = (unsigned)(16384 + buf * 24576 + s * 4096 + w * 1024);
            __builtin_amdgcn_global_load_lds(
                (const __attribute__((address_space(1))) void*)gp,
                (__attribute__((address_space(3))) void*)(ldsraw + base), 16, 0, 0);
        }
    };

    int arow = wm * 16 + lr;

    stage(0, 0);
    __syncthreads();

    for (int kt = 0; kt < 16; ++kt) {
        int cur = kt & 1;
        if (kt < 15) stage(kt + 1, cur ^ 1);

        const char* xb = ldsraw + cur * 8192 + arow * 256;
        const char* wb = ldsraw + 16384 + cur * 24576;
#pragma unroll
        for (int ks = 0; ks < 2; ++ks) {
            int g0 = ks * 8 + lg * 2;
            f32x4 u0 = *(const f32x4*)(xb + ((g0)     ^ lr) * 16);
            f32x4 u1 = *(const f32x4*)(xb + ((g0 + 1) ^ lr) * 16);
            bf16x8 a;
#pragma unroll
            for (int j = 0; j < 4; ++j) { a[j] = f2bf(u0[j]); a[4 + j] = f2bf(u1[j]); }
            int slot = (ks * 4 + lg) ^ (lr & 7);
#pragma unroll
            for (int nt = 0; nt < 6; ++nt) {
                int brow = wn * 96 + nt * 16 + lr;
                bf16x8 bf = *(const bf16x8*)(wb + brow * 128 + slot * 16);
                acc[nt] = MFMA16(a, bf, acc[nt], 0, 0, 0);
            }
        }
        __syncthreads();
    }

    // epilogue: scatter into fragment-tiled layouts
    int tg = t0 + wm * 16 + lg * 4;             // global row base (+r, same tile)
    int b = tg >> 11;
    int s = (tg & 2047) >> 5;
    int w32b = tg & 31;                          // wm*16 + lg*4
#pragma unroll
    for (int nt = 0; nt < 6; ++nt) {
        int col0 = wn * 96 + nt * 16;
        int mat = col0 >> 6;
        int h = (col0 & 63) + lr;
        if (mat == 2) {
            // V: c=w32>>4, hi2=(w32>>3)&1, j=(lg&1)*4+r ; lane'=hi2*32+(h&31)
            int ht = h >> 5;
            int c = w32b >> 4;
            int hi2 = (lg >> 1) & 1;
            int jb = (lg & 1) * 4;
            int lanep = hi2 * 32 + (h & 31);
            bf16x4 pk;
#pragma unroll
            for (int r = 0; r < 4; ++r) pk[r] = f2bf(acc[nt][r]);
            size_t idx = (((((size_t)b * 64 + s) * 2 + ht) * 2 + c) * 64 + lanep) * 8 + jb;
            *(bf16x4*)(vF + idx) = pk;
        } else {
            short* dst = mat ? qF : kF;
            int c = h >> 4, hi2 = (h >> 3) & 1, j = h & 7;
            size_t base = ((((size_t)b * 64 + s) * 4 + c) * 64 + hi2 * 32) * 8 + j;
#pragma unroll
            for (int r = 0; r < 4; ++r)
                dst[base + (size_t)(w32b + r) * 8] = f2bf(acc[nt][r]);
        }
    }
}

// ---- kernel 2: causal flash attention, 32x32 swapped MFMA, P in registers,
// fragment-tiled operands -> every load is lane-contiguous (coalesced).
__global__ __launch_bounds__(512, 4) void attn(const short* __restrict__ kF,
                                               const short* __restrict__ qF,
                                               const short* __restrict__ vF,
                                               float* __restrict__ out) {
    int bid = blockIdx.x;
    int b = bid & 7;                             // one batch per XCD
    int i = bid >> 3;                            // 0..63
    int ti = (i & 1) ? (63 - (i >> 1)) : (i >> 1);
    int t0 = ti * 32;

    int w = threadIdx.x >> 6;                    // kv-split 0..7
    int lane = threadIdx.x & 63;
    int q = lane & 31, hi = lane >> 5;

    __shared__ float lacc[8][32][65];
    __shared__ float lm[8][32], ll[8][32];

    const short* qp = qF + ((size_t)(b * 64 + ti)) * 2048 + lane * 8;
    bf16x8 qf0 = *(const bf16x8*)(qp);
    bf16x8 qf1 = *(const bf16x8*)(qp + 512);
    bf16x8 qf2 = *(const bf16x8*)(qp + 1024);
    bf16x8 qf3 = *(const bf16x8*)(qp + 1536);

    const short* kb_b = kF + (size_t)b * 64 * 2048 + lane * 8;
    const short* vb_b = vF + (size_t)b * 64 * 2048 + lane * 8;

    f32x16 acc0 = {}, acc1 = {};
    float m_s = -1e30f, l_s = 0.f;

    int nblk = ti + 1;                           // 32-kv blocks
    for (int blk = w; blk < nblk; blk += 8) {
        const short* kp = kb_b + (size_t)blk * 2048;
        bf16x8 kf0 = *(const bf16x8*)(kp);
        bf16x8 kf1 = *(const bf16x8*)(kp + 512);
        bf16x8 kf2 = *(const bf16x8*)(kp + 1024);
        bf16x8 kf3 = *(const bf16x8*)(kp + 1536);

        f32x16 S = {};
        S = MFMA32(kf0, qf0, S, 0, 0, 0);
        S = MFMA32(kf1, qf1, S, 0, 0, 0);
        S = MFMA32(kf2, qf2, S, 0, 0, 0);
        S = MFMA32(kf3, qf3, S, 0, 0, 0);

        const short* vp = vb_b + (size_t)blk * 2048;
        bf16x8 vf00 = *(const bf16x8*)(vp);          // ht=0,c=0
        bf16x8 vf01 = *(const bf16x8*)(vp + 512);    // ht=0,c=1
        bf16x8 vf10 = *(const bf16x8*)(vp + 1024);   // ht=1,c=0
        bf16x8 vf11 = *(const bf16x8*)(vp + 1536);   // ht=1,c=1

        if (blk == ti) {                         // diagonal: mask kv>q
#pragma unroll
            for (int r = 0; r < 16; ++r) {
                int row = (r & 3) + 8 * (r >> 2) + 4 * hi;
                if (row > q) S[r] = -1e30f;
            }
        }

        // lane-local softmax (lane owns q col; partner half via one shfl)
        float tm = S[0];
#pragma unroll
        for (int r = 1; r < 16; ++r) tm = fmaxf(tm, S[r]);
        tm = fmaxf(tm, __shfl_xor(tm, 32));
        float mn = fmaxf(m_s, tm);
        float fr = exp2f(m_s - mn);
        float p[16];
        float rs = 0.f;
#pragma unroll
        for (int r = 0; r < 16; ++r) { p[r] = exp2f(S[r] - mn); rs += p[r]; }
        rs += __shfl_xor(rs, 32);
        l_s = l_s * fr + rs;
        m_s = mn;

        // pack P to bf16 pairs, permlane-swap into PV B-frags
        unsigned pk0 = cvt_pk_bf16(p[0],  p[1]);
        unsigned pk1 = cvt_pk_bf16(p[2],  p[3]);
        unsigned pk2 = cvt_pk_bf16(p[4],  p[5]);
        unsigned pk3 = cvt_pk_bf16(p[6],  p[7]);
        unsigned pk4 = cvt_pk_bf16(p[8],  p[9]);
        unsigned pk5 = cvt_pk_bf16(p[10], p[11]);
        unsigned pk6 = cvt_pk_bf16(p[12], p[13]);
        unsigned pk7 = cvt_pk_bf16(p[14], p[15]);
        u32x2 s02 = __builtin_amdgcn_permlane32_swap(pk0, pk2, false, false);
        u32x2 s13 = __builtin_amdgcn_permlane32_swap(pk1, pk3, false, false);
        u32x2 s46 = __builtin_amdgcn_permlane32_swap(pk4, pk6, false, false);
        u32x2 s57 = __builtin_amdgcn_permlane32_swap(pk5, pk7, false, false);
        union { bf16x8 v; unsigned u[4]; } f0, f1;
        f0.u[0] = s02.x; f0.u[1] = s13.x; f0.u[2] = s02.y; f0.u[3] = s13.y;
        f1.u[0] = s46.x; f1.u[1] = s57.x; f1.u[2] = s46.y; f1.u[3] = s57.y;

        // rescale (fr lane-local) then PV
#pragma unroll
        for (int r = 0; r < 16; ++r) { acc0[r] *= fr; acc1[r] *= fr; }

        acc0 = MFMA32(vf00, f0.v, acc0, 0, 0, 0);
        acc0 = MFMA32(vf01, f1.v, acc0, 0, 0, 0);
        acc1 = MFMA32(vf10, f0.v, acc1, 0, 0, 0);
        acc1 = MFMA32(vf11, f1.v, acc1, 0, 0, 0);
    }

    // publish partials
    if (hi == 0) { lm[w][q] = m_s; ll[w][q] = l_s; }
#pragma unroll
    for (int r = 0; r < 16; ++r) {
        int row = (r & 3) + 8 * (r >> 2) + 4 * hi;
        lacc[w][q][row]      = acc0[r];
        lacc[w][q][32 + row] = acc1[r];
    }
    __syncthreads();

    // merge 8 partials; 512 threads x 4 elems = 32x64 outputs
    int tid = threadIdx.x;
#pragma unroll
    for (int e = 0; e < 4; ++e) {
        int elem = e * 512 + tid;
        int row = elem >> 6, col = elem & 63;
        float ms = lm[0][row];
#pragma unroll
        for (int j = 1; j < 8; ++j) ms = fmaxf(ms, lm[j][row]);
        float lsum = 0.f, asum = 0.f;
#pragma unroll
        for (int j = 0; j < 8; ++j) {
            float sj = exp2f(lm[j][row] - ms);
            lsum += ll[j][row] * sj;
            asum += lacc[j][row][col] * sj;
        }
        out[(size_t)(b * 2048 + t0 + row) * 64 + col] = asum / lsum;
    }
}

extern "C" void kernel_launch(void* const* d_in, const int* in_sizes, int n_in,
                              void* d_out, int out_size, void* d_ws, size_t ws_size,
                              hipStream_t stream) {
    (void)in_sizes; (void)n_in; (void)out_size; (void)ws_size;
    const float* x  = (const float*)d_in[0];
    const float* Wk = (const float*)d_in[1];
    const float* Wq = (const float*)d_in[2];
    const float* Wv = (const float*)d_in[3];
    float* out = (float*)d_out;

    char* ws = (char*)d_ws;
    short* wsT = (short*)(ws);                  // 384 KB
    short* kF  = (short*)(ws + (1u << 20));     // 2 MB
    short* qF  = (short*)(ws + (3u << 20));     // 2 MB
    short* vF  = (short*)(ws + (5u << 20));     // 2 MB

    prep_w<<<768, 256, 0, stream>>>(Wk, Wq, Wv, wsT);
    proj  <<<512, 256, 0, stream>>>(x, wsT, kF, qF, vF);
    attn  <<<512, 512, 0, stream>>>(kF, qF, vF, out);
}

// Round 7
// 43.477 us; speedup vs baseline: 3.3712x; 1.0187x over previous
//
#include <hip/hip_runtime.h>
#include <hip/hip_bf16.h>

// B=8, T=2048, E=1024, H=64 single-head causal attention.
// ws: wsT bf16 [192][1024] @0.
// kF/qF @1MB/@3MB: fragment-tiled K/Q, [b][s][c][lane][8]:
//   element = M[b][s*32 + (lane&31)][c*16 + (lane>>5)*8 + j]
// vF @5MB: fragment-tiled V, [b][s][ht][c][lane][8]:
//   element = V[b][s*32 + c*16 + (lane>>5)*8 + j][ht*32 + (lane&31)]

typedef float f32x4 __attribute__((ext_vector_type(4)));
typedef float f32x16 __attribute__((ext_vector_type(16)));
typedef short bf16x8 __attribute__((ext_vector_type(8)));
typedef short bf16x4 __attribute__((ext_vector_type(4)));
typedef unsigned u32x2 __attribute__((ext_vector_type(2)));

#define MFMA16 __builtin_amdgcn_mfma_f32_16x16x32_bf16
#define MFMA32 __builtin_amdgcn_mfma_f32_32x32x16_bf16

__device__ __forceinline__ short f2bf(float f) {
    union { float f; unsigned u; } c; c.f = f;
    unsigned u = c.u;
    return (short)((u + 0x7FFFu + ((u >> 16) & 1u)) >> 16);  // RNE
}

__device__ __forceinline__ unsigned cvt_pk_bf16(float lo, float hi) {
    unsigned r;
    asm("v_cvt_pk_bf16_f32 %0, %1, %2" : "=v"(r) : "v"(lo), "v"(hi));
    return r;
}

// ---- kernel 0: transpose+convert W -> wsT[192][1024] bf16; Wq scaled 0.125*log2e
__global__ __launch_bounds__(256) void prep_w(const float* __restrict__ Wk,
                                              const float* __restrict__ Wq,
                                              const float* __restrict__ Wv,
                                              short* __restrict__ wsT) {
    int idx = blockIdx.x * 256 + threadIdx.x;
    int r = idx >> 10;
    int k = idx & 1023;
    int mat = r >> 6, c = r & 63;
    const float* W = (mat == 0) ? Wk : (mat == 1) ? Wq : Wv;
    float v = W[k * 64 + c];
    if (mat == 1) v *= 0.125f * 1.44269504088896f;   // fold scale + log2(e)
    wsT[r * 1024 + k] = f2bf(v);
}

// ---- kernel 1: projections. 512 thr = 8 waves (wm 0..1 x wn 0..3, 48-col
// strips), BM=32, BK=64, both operands LDS-staged via global_load_lds.
__global__ __launch_bounds__(512, 4) void proj(const float* __restrict__ x,
                                               const short* __restrict__ wsT,
                                               short* __restrict__ kF,
                                               short* __restrict__ qF,
                                               short* __restrict__ vF) {
    __shared__ char ldsraw[2 * 8192 + 2 * 24576];   // xbuf[2] then wbuf[2]
    int tid = threadIdx.x;
    int w = tid >> 6, lane = tid & 63;
    int wm = w >> 2, wn = w & 3;
    int lr = lane & 15, lg = lane >> 4;
    int t0 = blockIdx.x * 32;

    f32x4 acc[3] = {};

    auto stage = [&](int kt, int buf) {
        int k0 = kt * 64;
        {   // x: 32 rows x 16 granules = 512 (1/thread)
            int G = tid;
            int row = G >> 4, p = G & 15;
            int g = p ^ (row & 15);
            const float* gp = x + (size_t)(t0 + row) * 1024 + k0 + g * 4;
            unsigned base = (unsigned)(buf * 8192 + w * 1024);
            __builtin_amdgcn_global_load_lds(
                (const __attribute__((address_space(1))) void*)gp,
                (__attribute__((address_space(3))) void*)(ldsraw + base), 16, 0, 0);
        }
#pragma unroll
        for (int s = 0; s < 3; ++s) {               // wsT: 192 rows x 8 granules
            int G = s * 512 + tid;
            int row = G >> 3, p = G & 7;
            int g = p ^ (row & 7);
            const short* gp = wsT + (size_t)row * 1024 + k0 + g * 8;
            unsigned base = (unsigned)(16384 + buf * 24576 + s * 8192 + w * 1024);
            __builtin_amdgcn_global_load_lds(
                (const __attribute__((address_space(1))) void*)gp,
                (__attribute__((address_space(3))) void*)(ldsraw + base), 16, 0, 0);
        }
    };

    int arow = wm * 16 + lr;                        // 0..31, arow&15 == lr

    stage(0, 0);
    __syncthreads();

    for (int kt = 0; kt < 16; ++kt) {
        int cur = kt & 1;
        if (kt < 15) stage(kt + 1, cur ^ 1);

        const char* xb = ldsraw + cur * 8192 + arow * 256;
        const char* wb = ldsraw + 16384 + cur * 24576;
#pragma unroll
        for (int ks = 0; ks < 2; ++ks) {
            int g0 = ks * 8 + lg * 2;
            f32x4 u0 = *(const f32x4*)(xb + ((g0)     ^ lr) * 16);
            f32x4 u1 = *(const f32x4*)(xb + ((g0 + 1) ^ lr) * 16);
            bf16x8 a;
#pragma unroll
            for (int j = 0; j < 4; ++j) { a[j] = f2bf(u0[j]); a[4 + j] = f2bf(u1[j]); }
            int slot = (ks * 4 + lg) ^ (lr & 7);
#pragma unroll
            for (int nt = 0; nt < 3; ++nt) {
                int brow = wn * 48 + nt * 16 + lr;
                bf16x8 bf = *(const bf16x8*)(wb + brow * 128 + slot * 16);
                acc[nt] = MFMA16(a, bf, acc[nt], 0, 0, 0);
            }
        }
        __syncthreads();                            // drains stage(kt+1) too
    }

    // epilogue: scatter into fragment-tiled layouts
    int tg = t0 + wm * 16 + lg * 4;
    int b = tg >> 11;
    int s = (tg & 2047) >> 5;
    int w32b = tg & 31;
#pragma unroll
    for (int nt = 0; nt < 3; ++nt) {
        int col0 = wn * 48 + nt * 16;
        int mat = col0 >> 6;
        int h = (col0 & 63) + lr;
        if (mat == 2) {
            int ht = h >> 5;
            int c = w32b >> 4;
            int hi2 = (lg >> 1) & 1;
            int jb = (lg & 1) * 4;
            int lanep = hi2 * 32 + (h & 31);
            bf16x4 pk;
#pragma unroll
            for (int r = 0; r < 4; ++r) pk[r] = f2bf(acc[nt][r]);
            size_t idx = (((((size_t)b * 64 + s) * 2 + ht) * 2 + c) * 64 + lanep) * 8 + jb;
            *(bf16x4*)(vF + idx) = pk;
        } else {
            short* dst = mat ? qF : kF;
            int c = h >> 4, hi2 = (h >> 3) & 1, j = h & 7;
            size_t base = ((((size_t)b * 64 + s) * 4 + c) * 64 + hi2 * 32) * 8 + j;
#pragma unroll
            for (int r = 0; r < 4; ++r)
                dst[base + (size_t)(w32b + r) * 8] = f2bf(acc[nt][r]);
        }
    }
}

// ---- kernel 2: causal flash attention, 32x32 swapped MFMA, P in registers
// (exp2 in place on S -> no p[] array, VGPR <= 128), tree reductions,
// defer-rescale (exact, THR=0).
__global__ __launch_bounds__(512, 4) void attn(const short* __restrict__ kF,
                                               const short* __restrict__ qF,
                                               const short* __restrict__ vF,
                                               float* __restrict__ out) {
    int bid = blockIdx.x;
    int b = bid & 7;                             // one batch per XCD
    int i = bid >> 3;                            // 0..63
    int ti = (i & 1) ? (63 - (i >> 1)) : (i >> 1);
    int t0 = ti * 32;

    int w = threadIdx.x >> 6;                    // kv-split 0..7
    int lane = threadIdx.x & 63;
    int q = lane & 31, hi = lane >> 5;

    __shared__ float lacc[8][32][65];
    __shared__ float lm[8][32], ll[8][32];

    const short* qp = qF + ((size_t)(b * 64 + ti)) * 2048 + lane * 8;
    bf16x8 qf0 = *(const bf16x8*)(qp);
    bf16x8 qf1 = *(const bf16x8*)(qp + 512);
    bf16x8 qf2 = *(const bf16x8*)(qp + 1024);
    bf16x8 qf3 = *(const bf16x8*)(qp + 1536);

    const short* kb_b = kF + (size_t)b * 64 * 2048 + lane * 8;
    const short* vb_b = vF + (size_t)b * 64 * 2048 + lane * 8;

    f32x16 acc0 = {}, acc1 = {};
    float m_s = -1e30f, l_s = 0.f;

    int nblk = ti + 1;
    for (int blk = w; blk < nblk; blk += 8) {
        const short* kp = kb_b + (size_t)blk * 2048;
        bf16x8 kf0 = *(const bf16x8*)(kp);
        bf16x8 kf1 = *(const bf16x8*)(kp + 512);
        bf16x8 kf2 = *(const bf16x8*)(kp + 1024);
        bf16x8 kf3 = *(const bf16x8*)(kp + 1536);

        f32x16 S = {};
        S = MFMA32(kf0, qf0, S, 0, 0, 0);
        S = MFMA32(kf1, qf1, S, 0, 0, 0);
        S = MFMA32(kf2, qf2, S, 0, 0, 0);
        S = MFMA32(kf3, qf3, S, 0, 0, 0);

        const short* vp = vb_b + (size_t)blk * 2048;
        bf16x8 vf00 = *(const bf16x8*)(vp);
        bf16x8 vf01 = *(const bf16x8*)(vp + 512);
        bf16x8 vf10 = *(const bf16x8*)(vp + 1024);
        bf16x8 vf11 = *(const bf16x8*)(vp + 1536);

        if (blk == ti) {                         // diagonal: mask kv>q
#pragma unroll
            for (int r = 0; r < 16; ++r) {
                int row = (r & 3) + 8 * (r >> 2) + 4 * hi;
                if (row > q) S[r] = -1e30f;
            }
        }

        // tree max over 16 regs + cross-half shfl
        float a0 = fmaxf(S[0], S[1]),   a1 = fmaxf(S[2], S[3]);
        float a2 = fmaxf(S[4], S[5]),   a3 = fmaxf(S[6], S[7]);
        float a4 = fmaxf(S[8], S[9]),   a5 = fmaxf(S[10], S[11]);
        float a6 = fmaxf(S[12], S[13]), a7 = fmaxf(S[14], S[15]);
        a0 = fmaxf(a0, a1); a2 = fmaxf(a2, a3);
        a4 = fmaxf(a4, a5); a6 = fmaxf(a6, a7);
        a0 = fmaxf(a0, a2); a4 = fmaxf(a4, a6);
        float tm = fmaxf(a0, a4);
        tm = fmaxf(tm, __shfl_xor(tm, 32));

        bool skip = __all(tm <= m_s);            // defer-rescale (exact)
        float mn = skip ? m_s : fmaxf(m_s, tm);

        // exp2 in place; tree sum
#pragma unroll
        for (int r = 0; r < 16; ++r) S[r] = exp2f(S[r] - mn);
        float b0 = (S[0] + S[1]) + (S[2] + S[3]);
        float b1 = (S[4] + S[5]) + (S[6] + S[7]);
        float b2 = (S[8] + S[9]) + (S[10] + S[11]);
        float b3 = (S[12] + S[13]) + (S[14] + S[15]);
        float rs = (b0 + b1) + (b2 + b3);
        rs += __shfl_xor(rs, 32);

        if (skip) {
            l_s += rs;
        } else {
            float fr = exp2f(m_s - mn);
            l_s = l_s * fr + rs;
            m_s = mn;
#pragma unroll
            for (int r = 0; r < 16; ++r) { acc0[r] *= fr; acc1[r] *= fr; }
        }

        // pack P (from S) to bf16 pairs, permlane-swap into PV B-frags
        unsigned pk0 = cvt_pk_bf16(S[0],  S[1]);
        unsigned pk1 = cvt_pk_bf16(S[2],  S[3]);
        unsigned pk2 = cvt_pk_bf16(S[4],  S[5]);
        unsigned pk3 = cvt_pk_bf16(S[6],  S[7]);
        unsigned pk4 = cvt_pk_bf16(S[8],  S[9]);
        unsigned pk5 = cvt_pk_bf16(S[10], S[11]);
        unsigned pk6 = cvt_pk_bf16(S[12], S[13]);
        unsigned pk7 = cvt_pk_bf16(S[14], S[15]);
        u32x2 s02 = __builtin_amdgcn_permlane32_swap(pk0, pk2, false, false);
        u32x2 s13 = __builtin_amdgcn_permlane32_swap(pk1, pk3, false, false);
        u32x2 s46 = __builtin_amdgcn_permlane32_swap(pk4, pk6, false, false);
        u32x2 s57 = __builtin_amdgcn_permlane32_swap(pk5, pk7, false, false);
        union { bf16x8 v; unsigned u[4]; } f0, f1;
        f0.u[0] = s02.x; f0.u[1] = s13.x; f0.u[2] = s02.y; f0.u[3] = s13.y;
        f1.u[0] = s46.x; f1.u[1] = s57.x; f1.u[2] = s46.y; f1.u[3] = s57.y;

        acc0 = MFMA32(vf00, f0.v, acc0, 0, 0, 0);
        acc0 = MFMA32(vf01, f1.v, acc0, 0, 0, 0);
        acc1 = MFMA32(vf10, f0.v, acc1, 0, 0, 0);
        acc1 = MFMA32(vf11, f1.v, acc1, 0, 0, 0);
    }

    // publish partials
    if (hi == 0) { lm[w][q] = m_s; ll[w][q] = l_s; }
#pragma unroll
    for (int r = 0; r < 16; ++r) {
        int row = (r & 3) + 8 * (r >> 2) + 4 * hi;
        lacc[w][q][row]      = acc0[r];
        lacc[w][q][32 + row] = acc1[r];
    }
    __syncthreads();

    // merge 8 partials; 512 threads x 4 elems = 32x64 outputs
    int tid = threadIdx.x;
#pragma unroll
    for (int e = 0; e < 4; ++e) {
        int elem = e * 512 + tid;
        int row = elem >> 6, col = elem & 63;
        float ms = lm[0][row];
#pragma unroll
        for (int j = 1; j < 8; ++j) ms = fmaxf(ms, lm[j][row]);
        float lsum = 0.f, asum = 0.f;
#pragma unroll
        for (int j = 0; j < 8; ++j) {
            float sj = exp2f(lm[j][row] - ms);
            lsum += ll[j][row] * sj;
            asum += lacc[j][row][col] * sj;
        }
        out[(size_t)(b * 2048 + t0 + row) * 64 + col] = asum / lsum;
    }
}

extern "C" void kernel_launch(void* const* d_in, const int* in_sizes, int n_in,
                              void* d_out, int out_size, void* d_ws, size_t ws_size,
                              hipStream_t stream) {
    (void)in_sizes; (void)n_in; (void)out_size; (void)ws_size;
    const float* x  = (const float*)d_in[0];
    const float* Wk = (const float*)d_in[1];
    const float* Wq = (const float*)d_in[2];
    const float* Wv = (const float*)d_in[3];
    float* out = (float*)d_out;

    char* ws = (char*)d_ws;
    short* wsT = (short*)(ws);                  // 384 KB
    short* kF  = (short*)(ws + (1u << 20));     // 2 MB
    short* qF  = (short*)(ws + (3u << 20));     // 2 MB
    short* vF  = (short*)(ws + (5u << 20));     // 2 MB

    prep_w<<<768, 256, 0, stream>>>(Wk, Wq, Wv, wsT);
    proj  <<<512, 512, 0, stream>>>(x, wsT, kF, qF, vF);
    attn  <<<512, 512, 0, stream>>>(kF, qF, vF, out);
}

// Round 8
// 42.048 us; speedup vs baseline: 3.4858x; 1.0340x over previous
//
#include <hip/hip_runtime.h>
#include <hip/hip_bf16.h>

// B=8, T=2048, E=1024, H=64 single-head causal attention.
// ws: wsT bf16 [192][1024] @0.
// kF/qF @1MB/@3MB: fragment-tiled K/Q, [b][s][c][lane][8]:
//   element = M[b][s*32 + (lane&31)][c*16 + (lane>>5)*8 + j]
// vF @5MB: fragment-tiled V, [b][s][ht][c][lane][8]:
//   element = V[b][s*32 + c*16 + (lane>>5)*8 + j][ht*32 + (lane&31)]

typedef float f32x4 __attribute__((ext_vector_type(4)));
typedef float f32x16 __attribute__((ext_vector_type(16)));
typedef short bf16x8 __attribute__((ext_vector_type(8)));
typedef short bf16x4 __attribute__((ext_vector_type(4)));
typedef unsigned u32x2 __attribute__((ext_vector_type(2)));

#define MFMA16 __builtin_amdgcn_mfma_f32_16x16x32_bf16
#define MFMA32 __builtin_amdgcn_mfma_f32_32x32x16_bf16

__device__ __forceinline__ short f2bf(float f) {
    union { float f; unsigned u; } c; c.f = f;
    unsigned u = c.u;
    return (short)((u + 0x7FFFu + ((u >> 16) & 1u)) >> 16);  // RNE
}

__device__ __forceinline__ unsigned cvt_pk_bf16(float lo, float hi) {
    unsigned r;
    asm("v_cvt_pk_bf16_f32 %0, %1, %2" : "=v"(r) : "v"(lo), "v"(hi));
    return r;
}

// ---- kernel 0: transpose+convert W -> wsT[192][1024] bf16; Wq scaled 0.125*log2e
__global__ __launch_bounds__(256) void prep_w(const float* __restrict__ Wk,
                                              const float* __restrict__ Wq,
                                              const float* __restrict__ Wv,
                                              short* __restrict__ wsT) {
    int idx = blockIdx.x * 256 + threadIdx.x;
    int r = idx >> 10;
    int k = idx & 1023;
    int mat = r >> 6, c = r & 63;
    const float* W = (mat == 0) ? Wk : (mat == 1) ? Wq : Wv;
    float v = W[k * 64 + c];
    if (mat == 1) v *= 0.125f * 1.44269504088896f;   // fold scale + log2(e)
    wsT[r * 1024 + k] = f2bf(v);
}

// ---- kernel 1: projections (BYTE-IDENTICAL to round 7 — control variable).
__global__ __launch_bounds__(512, 4) void proj(const float* __restrict__ x,
                                               const short* __restrict__ wsT,
                                               short* __restrict__ kF,
                                               short* __restrict__ qF,
                                               short* __restrict__ vF) {
    __shared__ char ldsraw[2 * 8192 + 2 * 24576];   // xbuf[2] then wbuf[2]
    int tid = threadIdx.x;
    int w = tid >> 6, lane = tid & 63;
    int wm = w >> 2, wn = w & 3;
    int lr = lane & 15, lg = lane >> 4;
    int t0 = blockIdx.x * 32;

    f32x4 acc[3] = {};

    auto stage = [&](int kt, int buf) {
        int k0 = kt * 64;
        {
            int G = tid;
            int row = G >> 4, p = G & 15;
            int g = p ^ (row & 15);
            const float* gp = x + (size_t)(t0 + row) * 1024 + k0 + g * 4;
            unsigned base = (unsigned)(buf * 8192 + w * 1024);
            __builtin_amdgcn_global_load_lds(
                (const __attribute__((address_space(1))) void*)gp,
                (__attribute__((address_space(3))) void*)(ldsraw + base), 16, 0, 0);
        }
#pragma unroll
        for (int s = 0; s < 3; ++s) {
            int G = s * 512 + tid;
            int row = G >> 3, p = G & 7;
            int g = p ^ (row & 7);
            const short* gp = wsT + (size_t)row * 1024 + k0 + g * 8;
            unsigned base = (unsigned)(16384 + buf * 24576 + s * 8192 + w * 1024);
            __builtin_amdgcn_global_load_lds(
                (const __attribute__((address_space(1))) void*)gp,
                (__attribute__((address_space(3))) void*)(ldsraw + base), 16, 0, 0);
        }
    };

    int arow = wm * 16 + lr;

    stage(0, 0);
    __syncthreads();

    for (int kt = 0; kt < 16; ++kt) {
        int cur = kt & 1;
        if (kt < 15) stage(kt + 1, cur ^ 1);

        const char* xb = ldsraw + cur * 8192 + arow * 256;
        const char* wb = ldsraw + 16384 + cur * 24576;
#pragma unroll
        for (int ks = 0; ks < 2; ++ks) {
            int g0 = ks * 8 + lg * 2;
            f32x4 u0 = *(const f32x4*)(xb + ((g0)     ^ lr) * 16);
            f32x4 u1 = *(const f32x4*)(xb + ((g0 + 1) ^ lr) * 16);
            bf16x8 a;
#pragma unroll
            for (int j = 0; j < 4; ++j) { a[j] = f2bf(u0[j]); a[4 + j] = f2bf(u1[j]); }
            int slot = (ks * 4 + lg) ^ (lr & 7);
#pragma unroll
            for (int nt = 0; nt < 3; ++nt) {
                int brow = wn * 48 + nt * 16 + lr;
                bf16x8 bf = *(const bf16x8*)(wb + brow * 128 + slot * 16);
                acc[nt] = MFMA16(a, bf, acc[nt], 0, 0, 0);
            }
        }
        __syncthreads();
    }

    int tg = t0 + wm * 16 + lg * 4;
    int b = tg >> 11;
    int s = (tg & 2047) >> 5;
    int w32b = tg & 31;
#pragma unroll
    for (int nt = 0; nt < 3; ++nt) {
        int col0 = wn * 48 + nt * 16;
        int mat = col0 >> 6;
        int h = (col0 & 63) + lr;
        if (mat == 2) {
            int ht = h >> 5;
            int c = w32b >> 4;
            int hi2 = (lg >> 1) & 1;
            int jb = (lg & 1) * 4;
            int lanep = hi2 * 32 + (h & 31);
            bf16x4 pk;
#pragma unroll
            for (int r = 0; r < 4; ++r) pk[r] = f2bf(acc[nt][r]);
            size_t idx = (((((size_t)b * 64 + s) * 2 + ht) * 2 + c) * 64 + lanep) * 8 + jb;
            *(bf16x4*)(vF + idx) = pk;
        } else {
            short* dst = mat ? qF : kF;
            int c = h >> 4, hi2 = (h >> 3) & 1, j = h & 7;
            size_t base = ((((size_t)b * 64 + s) * 4 + c) * 64 + hi2 * 32) * 8 + j;
#pragma unroll
            for (int r = 0; r < 4; ++r)
                dst[base + (size_t)(w32b + r) * 8] = f2bf(acc[nt][r]);
        }
    }
}

// ---- kernel 2: causal flash attention v4. 256 blocks (1/CU), each handles
// the balanced tile pair (pj, 63-pj): 65 iterations per block, uniform.
// 8 waves kv-split; explicit next-K/V register prefetch; no VGPR cap (no
// spills; 8 waves/block = 2/SIMD resident); defer-rescale THR=11.5 (=e^8).
__global__ __launch_bounds__(512) void attn(const short* __restrict__ kF,
                                            const short* __restrict__ qF,
                                            const short* __restrict__ vF,
                                            float* __restrict__ out) {
    int bid = blockIdx.x;
    int b = bid & 7;                             // one batch per XCD
    int pj = bid >> 3;                           // 0..31

    int w = threadIdx.x >> 6;                    // kv-split 0..7
    int lane = threadIdx.x & 63;
    int q = lane & 31, hi = lane >> 5;
    int tid = threadIdx.x;

    __shared__ float lacc[8][32][65];
    __shared__ float lm[8][32], ll[8][32];

    const short* kb_b = kF + (size_t)b * 64 * 2048 + lane * 8;
    const short* vb_b = vF + (size_t)b * 64 * 2048 + lane * 8;

    for (int sel = 0; sel < 2; ++sel) {
        int ti = sel ? (63 - pj) : pj;
        int t0 = ti * 32;
        int nblk = ti + 1;

        const short* qp = qF + ((size_t)(b * 64 + ti)) * 2048 + lane * 8;
        bf16x8 qf0 = *(const bf16x8*)(qp);
        bf16x8 qf1 = *(const bf16x8*)(qp + 512);
        bf16x8 qf2 = *(const bf16x8*)(qp + 1024);
        bf16x8 qf3 = *(const bf16x8*)(qp + 1536);

        f32x16 acc0 = {}, acc1 = {};
        float m_s = -1e30f, l_s = 0.f;

        // prime the pipeline (safe address even when this wave has no work)
        int fb = (w < nblk) ? w : 0;
        const short* kp = kb_b + (size_t)fb * 2048;
        const short* vp = vb_b + (size_t)fb * 2048;
        bf16x8 kc0 = *(const bf16x8*)(kp);
        bf16x8 kc1 = *(const bf16x8*)(kp + 512);
        bf16x8 kc2 = *(const bf16x8*)(kp + 1024);
        bf16x8 kc3 = *(const bf16x8*)(kp + 1536);
        bf16x8 vc0 = *(const bf16x8*)(vp);
        bf16x8 vc1 = *(const bf16x8*)(vp + 512);
        bf16x8 vc2 = *(const bf16x8*)(vp + 1024);
        bf16x8 vc3 = *(const bf16x8*)(vp + 1536);

        for (int blk = w; blk < nblk; blk += 8) {
            // prefetch next tile (clamped address; last-iter loads are wasted L2 hits)
            int nxt = blk + 8;
            int ns = (nxt < nblk) ? nxt : blk;
            const short* kpn = kb_b + (size_t)ns * 2048;
            const short* vpn = vb_b + (size_t)ns * 2048;
            bf16x8 kn0 = *(const bf16x8*)(kpn);
            bf16x8 kn1 = *(const bf16x8*)(kpn + 512);
            bf16x8 kn2 = *(const bf16x8*)(kpn + 1024);
            bf16x8 kn3 = *(const bf16x8*)(kpn + 1536);
            bf16x8 vn0 = *(const bf16x8*)(vpn);
            bf16x8 vn1 = *(const bf16x8*)(vpn + 512);
            bf16x8 vn2 = *(const bf16x8*)(vpn + 1024);
            bf16x8 vn3 = *(const bf16x8*)(vpn + 1536);

            f32x16 S = {};
            S = MFMA32(kc0, qf0, S, 0, 0, 0);
            S = MFMA32(kc1, qf1, S, 0, 0, 0);
            S = MFMA32(kc2, qf2, S, 0, 0, 0);
            S = MFMA32(kc3, qf3, S, 0, 0, 0);

            if (blk == ti) {                     // diagonal: mask kv>q
#pragma unroll
                for (int r = 0; r < 16; ++r) {
                    int row = (r & 3) + 8 * (r >> 2) + 4 * hi;
                    if (row > q) S[r] = -1e30f;
                }
            }

            // tree max + cross-half shfl
            float a0 = fmaxf(S[0], S[1]),   a1 = fmaxf(S[2], S[3]);
            float a2 = fmaxf(S[4], S[5]),   a3 = fmaxf(S[6], S[7]);
            float a4 = fmaxf(S[8], S[9]),   a5 = fmaxf(S[10], S[11]);
            float a6 = fmaxf(S[12], S[13]), a7 = fmaxf(S[14], S[15]);
            a0 = fmaxf(a0, a1); a2 = fmaxf(a2, a3);
            a4 = fmaxf(a4, a5); a6 = fmaxf(a6, a7);
            a0 = fmaxf(a0, a2); a4 = fmaxf(a4, a6);
            float tm = fmaxf(a0, a4);
            tm = fmaxf(tm, __shfl_xor(tm, 32));

            // defer-rescale: P bounded by 2^11.5 (= e^8), exact in f32
            bool skip = __all(tm <= m_s + 11.5f);
            float mn = skip ? m_s : fmaxf(m_s, tm);

#pragma unroll
            for (int r = 0; r < 16; ++r) S[r] = exp2f(S[r] - mn);
            float b0 = (S[0] + S[1]) + (S[2] + S[3]);
            float b1 = (S[4] + S[5]) + (S[6] + S[7]);
            float b2 = (S[8] + S[9]) + (S[10] + S[11]);
            float b3 = (S[12] + S[13]) + (S[14] + S[15]);
            float rs = (b0 + b1) + (b2 + b3);
            rs += __shfl_xor(rs, 32);

            if (skip) {
                l_s += rs;
            } else {
                float fr = exp2f(m_s - mn);
                l_s = l_s * fr + rs;
                m_s = mn;
#pragma unroll
                for (int r = 0; r < 16; ++r) { acc0[r] *= fr; acc1[r] *= fr; }
            }

            // pack P, permlane-swap into PV B-frags
            unsigned pk0 = cvt_pk_bf16(S[0],  S[1]);
            unsigned pk1 = cvt_pk_bf16(S[2],  S[3]);
            unsigned pk2 = cvt_pk_bf16(S[4],  S[5]);
            unsigned pk3 = cvt_pk_bf16(S[6],  S[7]);
            unsigned pk4 = cvt_pk_bf16(S[8],  S[9]);
            unsigned pk5 = cvt_pk_bf16(S[10], S[11]);
            unsigned pk6 = cvt_pk_bf16(S[12], S[13]);
            unsigned pk7 = cvt_pk_bf16(S[14], S[15]);
            u32x2 s02 = __builtin_amdgcn_permlane32_swap(pk0, pk2, false, false);
            u32x2 s13 = __builtin_amdgcn_permlane32_swap(pk1, pk3, false, false);
            u32x2 s46 = __builtin_amdgcn_permlane32_swap(pk4, pk6, false, false);
            u32x2 s57 = __builtin_amdgcn_permlane32_swap(pk5, pk7, false, false);
            union { bf16x8 v; unsigned u[4]; } f0, f1;
            f0.u[0] = s02.x; f0.u[1] = s13.x; f0.u[2] = s02.y; f0.u[3] = s13.y;
            f1.u[0] = s46.x; f1.u[1] = s57.x; f1.u[2] = s46.y; f1.u[3] = s57.y;

            acc0 = MFMA32(vc0, f0.v, acc0, 0, 0, 0);
            acc0 = MFMA32(vc1, f1.v, acc0, 0, 0, 0);
            acc1 = MFMA32(vc2, f0.v, acc1, 0, 0, 0);
            acc1 = MFMA32(vc3, f1.v, acc1, 0, 0, 0);

            kc0 = kn0; kc1 = kn1; kc2 = kn2; kc3 = kn3;
            vc0 = vn0; vc1 = vn1; vc2 = vn2; vc3 = vn3;
        }

        // publish partials
        if (hi == 0) { lm[w][q] = m_s; ll[w][q] = l_s; }
#pragma unroll
        for (int r = 0; r < 16; ++r) {
            int row = (r & 3) + 8 * (r >> 2) + 4 * hi;
            lacc[w][q][row]      = acc0[r];
            lacc[w][q][32 + row] = acc1[r];
        }
        __syncthreads();

        // merge 8 partials; 512 threads x 4 elems = 32x64 outputs
#pragma unroll
        for (int e = 0; e < 4; ++e) {
            int elem = e * 512 + tid;
            int row = elem >> 6, col = elem & 63;
            float ms = lm[0][row];
#pragma unroll
            for (int j = 1; j < 8; ++j) ms = fmaxf(ms, lm[j][row]);
            float lsum = 0.f, asum = 0.f;
#pragma unroll
            for (int j = 0; j < 8; ++j) {
                float sj = exp2f(lm[j][row] - ms);
                lsum += ll[j][row] * sj;
                asum += lacc[j][row][col] * sj;
            }
            out[(size_t)(b * 2048 + t0 + row) * 64 + col] = asum / lsum;
        }
        __syncthreads();                         // lacc reuse for second tile
    }
}

extern "C" void kernel_launch(void* const* d_in, const int* in_sizes, int n_in,
                              void* d_out, int out_size, void* d_ws, size_t ws_size,
                              hipStream_t stream) {
    (void)in_sizes; (void)n_in; (void)out_size; (void)ws_size;
    const float* x  = (const float*)d_in[0];
    const float* Wk = (const float*)d_in[1];
    const float* Wq = (const float*)d_in[2];
    const float* Wv = (const float*)d_in[3];
    float* out = (float*)d_out;

    char* ws = (char*)d_ws;
    short* wsT = (short*)(ws);                  // 384 KB
    short* kF  = (short*)(ws + (1u << 20));     // 2 MB
    short* qF  = (short*)(ws + (3u << 20));     // 2 MB
    short* vF  = (short*)(ws + (5u << 20));     // 2 MB

    prep_w<<<768, 256, 0, stream>>>(Wk, Wq, Wv, wsT);
    proj  <<<512, 512, 0, stream>>>(x, wsT, kF, qF, vF);
    attn  <<<256, 512, 0, stream>>>(kF, qF, vF, out);
}